// Round 1
// baseline (4662.794 us; speedup 1.0000x reference)
//
#include <hip/hip_runtime.h>

constexpr int BB = 4, TT = 12, NN = 20000, FIN = 2;
constexpr int HID = 64, OUTC = 5;
constexpr int FIL = 32;
constexpr int T1n = 10, T2n = 8;

// ---------------- workspace layout (bytes) ----------------
constexpr size_t SZ_SL64 = (size_t)T1n * NN * HID * 4;        // 51,200,000 (10 slices of N x 64)
constexpr size_t SZ_H3   = (size_t)T2n * BB * NN * OUTC * 4;  // 12,800,000
constexpr size_t O_X   = 0;
constexpr size_t O_T1  = SZ_SL64;
constexpr size_t O_T2  = 2 * SZ_SL64;
constexpr size_t O_H3  = 3 * SZ_SL64;
constexpr size_t O_PX  = O_H3 + SZ_H3;
constexpr size_t O_BNS = O_PX + SZ_H3;
constexpr size_t O_BNH = O_BNS + 80000;
constexpr size_t O_DEG = O_BNH + 80000;
constexpr size_t O_IND = O_DEG + 80000;
constexpr size_t O_CUR = O_IND + 80000;
constexpr size_t O_DNV = O_CUR + 80000;
constexpr size_t O_RP  = O_DNV + 80000;      // (N+1)*4 = 80004, padded
constexpr size_t O_COL = O_RP + 80128;
constexpr size_t O_WCS = O_COL + 1280000;    // E*4
constexpr size_t O_LG  = O_WCS + 1280000;    // logits B*T2*N
constexpr size_t WS_NEED = O_LG + (size_t)BB * T2n * NN * 4;
// GRU state buffers reuse the X region (free after tc2 of last b):
constexpr size_t SZ_H = (size_t)BB * NN * FIL * 4;            // 10,240,000

// ---------------- graph preprocessing ----------------
__global__ void __launch_bounds__(256) k_edge_count(const int* __restrict__ ei, int E,
                                                    float* __restrict__ degf, int* __restrict__ indeg) {
  int e = blockIdx.x * 256 + threadIdx.x;
  if (e >= E) return;
  int s = ei[e], d = ei[E + e];
  if (s != d) {
    atomicAdd(&degf[s], 1.0f);   // integer counts in f32: exact
    atomicAdd(&indeg[d], 1);
  }
}

__global__ void __launch_bounds__(256) k_dinv(const float* __restrict__ degf, float* __restrict__ dinv) {
  int n = blockIdx.x * 256 + threadIdx.x;
  if (n >= NN) return;
  float d = degf[n];
  dinv[n] = d > 0.f ? rsqrtf(d) : 0.f;
}

__global__ void __launch_bounds__(1024) k_scan(const int* __restrict__ indeg, int* __restrict__ rowptr) {
  __shared__ int part[1024];
  const int chunk = (NN + 1023) / 1024;
  int t = threadIdx.x;
  int beg = t * chunk, end = min(beg + chunk, NN);
  int s = 0;
  for (int i = beg; i < end; ++i) s += indeg[i];
  part[t] = s;
  __syncthreads();
  if (t == 0) {
    int run = 0;
    for (int i = 0; i < 1024; ++i) { int v = part[i]; part[i] = run; run += v; }
    rowptr[NN] = run;
  }
  __syncthreads();
  int run = part[t];
  for (int i = beg; i < end; ++i) { rowptr[i] = run; run += indeg[i]; }
}

__global__ void __launch_bounds__(256) k_fill(const int* __restrict__ ei, int E,
                                              const float* __restrict__ dinv,
                                              const int* __restrict__ rowptr,
                                              int* __restrict__ cursor,
                                              int* __restrict__ col, float* __restrict__ wcs) {
  int e = blockIdx.x * 256 + threadIdx.x;
  if (e >= E) return;
  int s = ei[e], d = ei[E + e];
  if (s != d) {
    int p = atomicAdd(&cursor[d], 1);
    int o = rowptr[d] + p;
    col[o] = s;
    wcs[o] = -dinv[s] * dinv[d];
  }
}

// ---------------- temporal conv 1: (B,T,N,2) -> per-b (10,N,64) ----------------
__global__ void __launch_bounds__(256) k_tc1(const float* __restrict__ x, const float* __restrict__ W,
                                             const float* __restrict__ Bv, float* __restrict__ out, int b) {
  __shared__ float ws[1152];  // (3 convs, 3 k, 2 ci, 64 co)
  __shared__ float bs[192];
  for (int i = threadIdx.x; i < 1152; i += 256) ws[i] = W[i];
  for (int i = threadIdx.x; i < 192; i += 256) bs[i] = Bv[i];
  __syncthreads();
  long tid = (long)blockIdx.x * 256 + threadIdx.x;
  if (tid >= (long)T1n * NN * 64) return;
  int co = (int)(tid & 63);
  int n  = (int)((tid >> 6) % NN);
  int to = (int)(tid / (64L * NN));
  float aP = bs[co], aQ = bs[64 + co], aR = bs[128 + co];
#pragma unroll
  for (int k = 0; k < 3; ++k) {
#pragma unroll
    for (int ci = 0; ci < 2; ++ci) {
      float xv = x[(((long)b * TT + to + k) * NN + n) * FIN + ci];
      int wi = (k * 2 + ci) * 64 + co;
      aP = fmaf(xv, ws[wi], aP);
      aQ = fmaf(xv, ws[384 + wi], aQ);
      aR = fmaf(xv, ws[768 + wi], aR);
    }
  }
  float sq = 1.f / (1.f + expf(-aQ));
  out[tid] = fmaxf(aP * sq + aR, 0.f);
}

// ---------------- generic CSR propagation: out[s,n,:] = sum_e w[e]*v[s,col[e],:] ----------------
// if xin != nullptr: out = 2*acc - xin   (Chebyshev T2 fused)
template <int C, int LPN>
__global__ void __launch_bounds__(256) k_prop(const float* __restrict__ v, float* __restrict__ out,
                                              const float* __restrict__ xin,
                                              const int* __restrict__ rowptr, const int* __restrict__ col,
                                              const float* __restrict__ wcs, int S) {
  long tid = (long)blockIdx.x * 256 + threadIdx.x;
  long ng = tid / LPN;
  int c = (int)(tid % LPN);
  if (ng >= (long)S * NN) return;
  int s = (int)(ng / NN);
  int n = (int)(ng % NN);
  if constexpr (LPN == 64) {  // node is wave-uniform: force scalar edge loop
    n = __builtin_amdgcn_readfirstlane(n);
    s = __builtin_amdgcn_readfirstlane(s);
  }
  if (c < C) {
    int beg = rowptr[n], end = rowptr[n + 1];
    const float* vs = v + (long)s * NN * C;
    float acc = 0.f;
    for (int e = beg; e < end; ++e)
      acc = fmaf(wcs[e], vs[(long)col[e] * C + c], acc);
    long oi = ((long)s * NN + n) * C + c;
    out[oi] = xin ? (2.f * acc - xin[oi]) : acc;
  }
}

// ---------------- Cheb combine: out = relu([X|T1|T2] @ W(192x64) + b), in-place over X ----------------
__global__ void __launch_bounds__(256) k_cheb_combine(const float4* X4,
                                                      const float4* __restrict__ T14,
                                                      const float4* __restrict__ T24,
                                                      const float* __restrict__ W,
                                                      const float* __restrict__ Bv,
                                                      float* out, long rows) {
  long row = (long)blockIdx.x * 256 + threadIdx.x;
  if (row >= rows) return;
  float acc[64];
#pragma unroll
  for (int j = 0; j < 64; ++j) acc[j] = Bv[j];
#pragma unroll
  for (int k = 0; k < 3; ++k) {
    const float4* src = (k == 0) ? X4 : (k == 1) ? T14 : T24;
    const float* Wk = W + k * 4096;
    for (int c4 = 0; c4 < 16; ++c4) {               // runtime loop; weights are wave-uniform -> s_load
      float4 vv = src[row * 16 + c4];
      const float* w0 = Wk + (c4 * 4) * 64;
#pragma unroll
      for (int j = 0; j < 64; ++j)
        acc[j] += vv.x * w0[j] + vv.y * w0[64 + j] + vv.z * w0[128 + j] + vv.w * w0[192 + j];
    }
  }
  float4* o4 = (float4*)(out + row * 64);
#pragma unroll
  for (int j = 0; j < 16; ++j)
    o4[j] = make_float4(fmaxf(acc[4 * j], 0.f), fmaxf(acc[4 * j + 1], 0.f),
                        fmaxf(acc[4 * j + 2], 0.f), fmaxf(acc[4 * j + 3], 0.f));
}

// ---------------- temporal conv 2: per-b (10,N,64) -> h3[t][b][n][5] ----------------
__global__ void __launch_bounds__(256) k_tc2(const float4* __restrict__ h2, const float* __restrict__ W,
                                             const float* __restrict__ Bv, float* __restrict__ h3, int b) {
  long tid = (long)blockIdx.x * 256 + threadIdx.x;
  if (tid >= (long)T2n * NN) return;
  int t2 = (int)(tid / NN), n = (int)(tid % NN);
  float p[5], q[5], r[5];
#pragma unroll
  for (int co = 0; co < 5; ++co) { p[co] = Bv[co]; q[co] = Bv[5 + co]; r[co] = Bv[10 + co]; }
#pragma unroll
  for (int k = 0; k < 3; ++k) {
    const float4* rowp = h2 + ((long)(t2 + k) * NN + n) * 16;
    for (int c4 = 0; c4 < 16; ++c4) {
      float4 vv = rowp[c4];
      const float* w = W + ((k * 64) + c4 * 4) * 5;  // conv0 base; conv stride 960
#pragma unroll
      for (int co = 0; co < 5; ++co) {
        p[co] += vv.x * w[co]        + vv.y * w[5 + co]    + vv.z * w[10 + co]   + vv.w * w[15 + co];
        q[co] += vv.x * w[960 + co]  + vv.y * w[965 + co]  + vv.z * w[970 + co]  + vv.w * w[975 + co];
        r[co] += vv.x * w[1920 + co] + vv.y * w[1925 + co] + vv.z * w[1930 + co] + vv.w * w[1935 + co];
      }
    }
  }
#pragma unroll
  for (int co = 0; co < 5; ++co) {
    float sq = 1.f / (1.f + expf(-q[co]));
    h3[((long)(t2 * 4 + b) * NN + n) * 5 + co] = fmaxf(p[co] * sq + r[co], 0.f);
  }
}

// ---------------- BatchNorm per node over (B,T2,OUT)=160 values ----------------
__global__ void __launch_bounds__(256) k_bn_stats(const float* __restrict__ h3,
                                                  const float* __restrict__ gamma,
                                                  const float* __restrict__ beta,
                                                  float* __restrict__ bnS, float* __restrict__ bnH) {
  long tid = (long)blockIdx.x * 256 + threadIdx.x;
  if (tid >= 4L * NN) return;
  int q = (int)(tid & 3);
  int n = (int)(tid >> 2);
  float s1 = 0.f, s2 = 0.f;
  for (int t = q * 2; t < q * 2 + 2; ++t)
    for (int b = 0; b < 4; ++b) {
      const float* p = h3 + ((long)(t * 4 + b) * NN + n) * 5;
#pragma unroll
      for (int co = 0; co < 5; ++co) { float v = p[co]; s1 += v; s2 += v * v; }
    }
  s1 += __shfl_xor(s1, 1, 4); s1 += __shfl_xor(s1, 2, 4);
  s2 += __shfl_xor(s2, 1, 4); s2 += __shfl_xor(s2, 2, 4);
  if (q == 0) {
    float mean = s1 * (1.f / 160.f);
    float var = s2 * (1.f / 160.f) - mean * mean;
    float sc = gamma[n] * rsqrtf(var + 1e-5f);
    bnS[n] = sc;
    bnH[n] = beta[n] - mean * sc;
  }
}

__global__ void __launch_bounds__(256) k_bn_apply(float* __restrict__ h3,
                                                  const float* __restrict__ bnS,
                                                  const float* __restrict__ bnH) {
  long tid = (long)blockIdx.x * 256 + threadIdx.x;
  if (tid >= 32L * NN * 5) return;
  int n = (int)((tid / 5) % NN);
  h3[tid] = fmaxf(h3[tid] * bnS[n] + bnH[n], 0.f);
}

// ---------------- GRU gate kernels (thread per (b,n); weights wave-uniform -> s_load) ----------------
__global__ void __launch_bounds__(256) k_gru_zr(const float* __restrict__ h3, const float* __restrict__ PX,
                                                const float* __restrict__ Hp, const float* __restrict__ PH,
                                                const float* __restrict__ wx, const float* __restrict__ bx,
                                                const float* __restrict__ wh, const float* __restrict__ bh,
                                                float* __restrict__ Z, float* __restrict__ HR, int t) {
  long tid = (long)blockIdx.x * 256 + threadIdx.x;
  if (tid >= 4L * NN) return;
  int b = (int)(tid / NN), n = (int)(tid % NN);
  long xrow = ((long)(t * 4 + b) * NN + n) * 5;
  long hrow = ((long)b * NN + n) * 32;
  float z[32], r[32];
#pragma unroll
  for (int j = 0; j < 32; ++j) { z[j] = bx[j] + bh[j]; r[j] = bx[32 + j] + bh[32 + j]; }
#pragma unroll
  for (int ci = 0; ci < 5; ++ci) {
    float xv = h3[xrow + ci], pv = PX[xrow + ci];
    const float* w00 = wx + 0 * 160 + ci * 32;
    const float* w01 = wx + 1 * 160 + ci * 32;
    const float* w10 = wx + 2 * 160 + ci * 32;
    const float* w11 = wx + 3 * 160 + ci * 32;
#pragma unroll
    for (int j = 0; j < 32; ++j) {
      z[j] += xv * w00[j] + pv * w01[j];
      r[j] += xv * w10[j] + pv * w11[j];
    }
  }
  for (int ci = 0; ci < 32; ++ci) {
    float hv = Hp[hrow + ci], pv = PH[hrow + ci];
    const float* w00 = wh + 0 * 1024 + ci * 32;
    const float* w01 = wh + 1 * 1024 + ci * 32;
    const float* w10 = wh + 2 * 1024 + ci * 32;
    const float* w11 = wh + 3 * 1024 + ci * 32;
#pragma unroll
    for (int j = 0; j < 32; ++j) {
      z[j] += hv * w00[j] + pv * w01[j];
      r[j] += hv * w10[j] + pv * w11[j];
    }
  }
#pragma unroll
  for (int j = 0; j < 32; ++j) {
    float zz = 1.f / (1.f + expf(-z[j]));
    float rr = 1.f / (1.f + expf(-r[j]));
    Z[hrow + j] = zz;
    HR[hrow + j] = Hp[hrow + j] * rr;
  }
}

__global__ void __launch_bounds__(256) k_gru_h(const float* __restrict__ h3, const float* __restrict__ PX,
                                               const float* __restrict__ Hp, const float* __restrict__ Z,
                                               const float* __restrict__ HR, const float* __restrict__ PHR,
                                               const float* __restrict__ wx, const float* __restrict__ bx,
                                               const float* __restrict__ wh, const float* __restrict__ bh,
                                               const float* __restrict__ lw, const float* __restrict__ lb,
                                               float* __restrict__ Hn, float* __restrict__ logits, int t) {
  long tid = (long)blockIdx.x * 256 + threadIdx.x;
  if (tid >= 4L * NN) return;
  int b = (int)(tid / NN), n = (int)(tid % NN);
  long xrow = ((long)(t * 4 + b) * NN + n) * 5;
  long hrow = ((long)b * NN + n) * 32;
  float a[32];
#pragma unroll
  for (int j = 0; j < 32; ++j) a[j] = bx[64 + j] + bh[64 + j];
#pragma unroll
  for (int ci = 0; ci < 5; ++ci) {
    float xv = h3[xrow + ci], pv = PX[xrow + ci];
    const float* w0 = wx + 4 * 160 + ci * 32;
    const float* w1 = wx + 5 * 160 + ci * 32;
#pragma unroll
    for (int j = 0; j < 32; ++j) a[j] += xv * w0[j] + pv * w1[j];
  }
  for (int ci = 0; ci < 32; ++ci) {
    float hv = HR[hrow + ci], pv = PHR[hrow + ci];
    const float* w0 = wh + 4 * 1024 + ci * 32;
    const float* w1 = wh + 5 * 1024 + ci * 32;
#pragma unroll
    for (int j = 0; j < 32; ++j) a[j] += hv * w0[j] + pv * w1[j];
  }
  float logit = lb[0];
#pragma unroll
  for (int j = 0; j < 32; ++j) {
    float zz = Z[hrow + j];
    float hn = zz * Hp[hrow + j] + (1.f - zz) * tanhf(a[j]);
    Hn[hrow + j] = hn;
    logit = fmaf(fmaxf(hn, 0.f), lw[j], logit);
  }
  logits[((long)b * 8 + t) * NN + n] = logit;
}

// ---------------- final log_softmax over the 8 time steps ----------------
__global__ void __launch_bounds__(256) k_logsoftmax(const float* __restrict__ logits, float* __restrict__ out) {
  long tid = (long)blockIdx.x * 256 + threadIdx.x;
  if (tid >= 4L * NN) return;
  int b = (int)(tid / NN), n = (int)(tid % NN);
  float l[8];
#pragma unroll
  for (int t = 0; t < 8; ++t) l[t] = logits[((long)b * 8 + t) * NN + n];
  float m = l[0];
#pragma unroll
  for (int t = 1; t < 8; ++t) m = fmaxf(m, l[t]);
  float s = 0.f;
#pragma unroll
  for (int t = 0; t < 8; ++t) s += expf(l[t] - m);
  float lse = m + logf(s);
#pragma unroll
  for (int t = 0; t < 8; ++t) out[((long)b * 8 + t) * NN + n] = l[t] - lse;
}

// ---------------- host orchestration ----------------
extern "C" void kernel_launch(void* const* d_in, const int* in_sizes, int n_in,
                              void* d_out, int out_size, void* d_ws, size_t ws_size,
                              hipStream_t stream) {
  const float* x     = (const float*)d_in[0];
  const int*   ei    = (const int*)d_in[1];
  const float* tc1w  = (const float*)d_in[2];
  const float* tc1b  = (const float*)d_in[3];
  const float* chebw = (const float*)d_in[4];
  const float* chebb = (const float*)d_in[5];
  const float* tc2w  = (const float*)d_in[6];
  const float* tc2b  = (const float*)d_in[7];
  const float* gam   = (const float*)d_in[8];
  const float* bet   = (const float*)d_in[9];
  const float* gwx   = (const float*)d_in[10];
  const float* gbx   = (const float*)d_in[11];
  const float* gwh   = (const float*)d_in[12];
  const float* gbh   = (const float*)d_in[13];
  const float* lw    = (const float*)d_in[14];
  const float* lb    = (const float*)d_in[15];
  float* out = (float*)d_out;
  int E = in_sizes[1] / 2;
  if (ws_size < WS_NEED) return;

  char* ws = (char*)d_ws;
  float* X    = (float*)(ws + O_X);
  float* Tb1  = (float*)(ws + O_T1);
  float* Tb2  = (float*)(ws + O_T2);
  float* h3   = (float*)(ws + O_H3);
  float* PX   = (float*)(ws + O_PX);
  float* bnS  = (float*)(ws + O_BNS);
  float* bnH  = (float*)(ws + O_BNH);
  float* degf = (float*)(ws + O_DEG);
  int*   ind  = (int*)(ws + O_IND);
  int*   cur  = (int*)(ws + O_CUR);
  float* dnv  = (float*)(ws + O_DNV);
  int*   rp   = (int*)(ws + O_RP);
  int*   col  = (int*)(ws + O_COL);
  float* wcs  = (float*)(ws + O_WCS);
  float* lg   = (float*)(ws + O_LG);
  // GRU buffers reuse the X region (free after the per-b pipeline)
  float* Hp  = (float*)(ws + O_X);
  float* Hn  = (float*)(ws + O_X + SZ_H);
  float* Zb  = (float*)(ws + O_X + 2 * SZ_H);
  float* HRb = (float*)(ws + O_X + 3 * SZ_H);
  float* PHb = (float*)(ws + O_X + 4 * SZ_H);
  float* PHRb = (float*)(ws + O_T1);

  // --- graph prep ---
  hipMemsetAsync(ws + O_DEG, 0, 240000, stream);  // degf, indeg, cursor (contiguous)
  unsigned gE = (unsigned)((E + 255) / 256);
  k_edge_count<<<gE, 256, 0, stream>>>(ei, E, degf, ind);
  k_dinv<<<(NN + 255) / 256, 256, 0, stream>>>(degf, dnv);
  k_scan<<<1, 1024, 0, stream>>>(ind, rp);
  k_fill<<<gE, 256, 0, stream>>>(ei, E, dnv, rp, cur, col, wcs);

  // --- per-batch STConv pipeline ---
  const long nTh64 = (long)T1n * NN * 64;
  unsigned g64 = (unsigned)((nTh64 + 255) / 256);
  for (int b = 0; b < 4; ++b) {
    k_tc1<<<g64, 256, 0, stream>>>(x, tc1w, tc1b, X, b);
    k_prop<64, 64><<<g64, 256, 0, stream>>>(X, Tb1, nullptr, rp, col, wcs, T1n);
    k_prop<64, 64><<<g64, 256, 0, stream>>>(Tb1, Tb2, X, rp, col, wcs, T1n);
    k_cheb_combine<<<(unsigned)(((long)T1n * NN + 255) / 256), 256, 0, stream>>>(
        (const float4*)X, (const float4*)Tb1, (const float4*)Tb2, chebw, chebb, X, (long)T1n * NN);
    k_tc2<<<(unsigned)(((long)T2n * NN + 255) / 256), 256, 0, stream>>>(
        (const float4*)X, tc2w, tc2b, h3, b);
  }

  // --- BatchNorm (per node) + relu ---
  k_bn_stats<<<(4 * NN + 255) / 256, 256, 0, stream>>>(h3, gam, bet, bnS, bnH);
  k_bn_apply<<<(unsigned)((32L * NN * 5 + 255) / 256), 256, 0, stream>>>(h3, bnS, bnH);

  // --- precompute prop(Xt) for all 32 (t,b) slices ---
  k_prop<5, 8><<<(unsigned)((32L * NN * 8 + 255) / 256), 256, 0, stream>>>(
      h3, PX, nullptr, rp, col, wcs, 32);

  // --- GConvGRU, 8 sequential steps ---
  hipMemsetAsync(Hp, 0, SZ_H, stream);
  float* hp = Hp;
  float* hn = Hn;
  unsigned g32 = (unsigned)((4L * NN * 32 + 255) / 256);
  unsigned gN = (unsigned)((4L * NN + 255) / 256);
  for (int t = 0; t < 8; ++t) {
    k_prop<32, 32><<<g32, 256, 0, stream>>>(hp, PHb, nullptr, rp, col, wcs, 4);
    k_gru_zr<<<gN, 256, 0, stream>>>(h3, PX, hp, PHb, gwx, gbx, gwh, gbh, Zb, HRb, t);
    k_prop<32, 32><<<g32, 256, 0, stream>>>(HRb, PHRb, nullptr, rp, col, wcs, 4);
    k_gru_h<<<gN, 256, 0, stream>>>(h3, PX, hp, Zb, HRb, PHRb, gwx, gbx, gwh, gbh, lw, lb, hn, lg, t);
    float* tmp = hp; hp = hn; hn = tmp;
  }

  k_logsoftmax<<<gN, 256, 0, stream>>>(lg, out);
}

// Round 2
// 3947.464 us; speedup vs baseline: 1.1812x; 1.1812x over previous
//
#include <hip/hip_runtime.h>

constexpr int BB = 4, TT = 12, NN = 20000, FIN = 2;
constexpr int HID = 64, OUTC = 5;
constexpr int FIL = 32;
constexpr int T1n = 10, T2n = 8;

// ---------------- workspace layout (bytes) ----------------
constexpr size_t SZ_SL64 = (size_t)T1n * NN * HID * 4;        // 51,200,000
constexpr size_t SZ_H3   = (size_t)T2n * BB * NN * OUTC * 4;  // 12,800,000
constexpr size_t O_X   = 0;
constexpr size_t O_T1  = SZ_SL64;
constexpr size_t O_T2  = 2 * SZ_SL64;
constexpr size_t O_H3  = 3 * SZ_SL64;
constexpr size_t O_PX  = O_H3 + SZ_H3;
constexpr size_t O_BNS = O_PX + SZ_H3;
constexpr size_t O_BNH = O_BNS + 80000;
constexpr size_t O_DEG = O_BNH + 80000;
constexpr size_t O_IND = O_DEG + 80000;
constexpr size_t O_CUR = O_IND + 80000;
constexpr size_t O_DNV = O_CUR + 80000;
constexpr size_t O_RP  = O_DNV + 80000;
constexpr size_t O_COL = O_RP + 80128;
constexpr size_t O_WCS = O_COL + 1280000;    // E*4
constexpr size_t O_LG  = O_WCS + 1280000;    // logits B*T2*N
constexpr size_t WS_NEED = O_LG + (size_t)BB * T2n * NN * 4;
constexpr size_t SZ_H = (size_t)BB * NN * FIL * 4;            // 10,240,000

// ---------------- XCD-chunked bijective block swizzle (m204) ----------------
__device__ __forceinline__ unsigned swz8(unsigned orig, unsigned nwg) {
  unsigned q = nwg >> 3, r = nwg & 7;
  unsigned xcd = orig & 7, off = orig >> 3;
  unsigned base = (xcd < r) ? xcd * (q + 1) : r * (q + 1) + (xcd - r) * q;
  return base + off;
}

// ---------------- graph preprocessing ----------------
__global__ void __launch_bounds__(256) k_edge_count(const int* __restrict__ ei, int E,
                                                    float* __restrict__ degf, int* __restrict__ indeg) {
  int e = blockIdx.x * 256 + threadIdx.x;
  if (e >= E) return;
  int s = ei[e], d = ei[E + e];
  if (s != d) {
    atomicAdd(&degf[s], 1.0f);
    atomicAdd(&indeg[d], 1);
  }
}

__global__ void __launch_bounds__(256) k_dinv(const float* __restrict__ degf, float* __restrict__ dinv) {
  int n = blockIdx.x * 256 + threadIdx.x;
  if (n >= NN) return;
  float d = degf[n];
  dinv[n] = d > 0.f ? rsqrtf(d) : 0.f;
}

__global__ void __launch_bounds__(1024) k_scan(const int* __restrict__ indeg, int* __restrict__ rowptr) {
  __shared__ int part[1024];
  const int chunk = (NN + 1023) / 1024;
  int t = threadIdx.x;
  int beg = t * chunk, end = min(beg + chunk, NN);
  int s = 0;
  for (int i = beg; i < end; ++i) s += indeg[i];
  part[t] = s;
  __syncthreads();
  if (t == 0) {
    int run = 0;
    for (int i = 0; i < 1024; ++i) { int v = part[i]; part[i] = run; run += v; }
    rowptr[NN] = run;
  }
  __syncthreads();
  int run = part[t];
  for (int i = beg; i < end; ++i) { rowptr[i] = run; run += indeg[i]; }
}

__global__ void __launch_bounds__(256) k_fill(const int* __restrict__ ei, int E,
                                              const float* __restrict__ dinv,
                                              const int* __restrict__ rowptr,
                                              int* __restrict__ cursor,
                                              int* __restrict__ col, float* __restrict__ wcs) {
  int e = blockIdx.x * 256 + threadIdx.x;
  if (e >= E) return;
  int s = ei[e], d = ei[E + e];
  if (s != d) {
    int p = atomicAdd(&cursor[d], 1);
    int o = rowptr[d] + p;
    col[o] = s;
    wcs[o] = -dinv[s] * dinv[d];
  }
}

// ---------------- temporal conv 1 ----------------
__global__ void __launch_bounds__(256) k_tc1(const float* __restrict__ x, const float* __restrict__ W,
                                             const float* __restrict__ Bv, float* __restrict__ out, int b) {
  __shared__ float ws[1152];
  __shared__ float bs[192];
  for (int i = threadIdx.x; i < 1152; i += 256) ws[i] = W[i];
  for (int i = threadIdx.x; i < 192; i += 256) bs[i] = Bv[i];
  __syncthreads();
  long tid = (long)blockIdx.x * 256 + threadIdx.x;
  if (tid >= (long)T1n * NN * 64) return;
  int co = (int)(tid & 63);
  int n  = (int)((tid >> 6) % NN);
  int to = (int)(tid / (64L * NN));
  float aP = bs[co], aQ = bs[64 + co], aR = bs[128 + co];
#pragma unroll
  for (int k = 0; k < 3; ++k) {
#pragma unroll
    for (int ci = 0; ci < 2; ++ci) {
      float xv = x[(((long)b * TT + to + k) * NN + n) * FIN + ci];
      int wi = (k * 2 + ci) * 64 + co;
      aP = fmaf(xv, ws[wi], aP);
      aQ = fmaf(xv, ws[384 + wi], aQ);
      aR = fmaf(xv, ws[768 + wi], aR);
    }
  }
  float sq = 1.f / (1.f + expf(-aQ));
  out[tid] = fmaxf(aP * sq + aR, 0.f);
}

// ---------------- generic CSR propagation (XCD-swizzled) ----------------
template <int C, int LPN>
__global__ void __launch_bounds__(256) k_prop(const float* __restrict__ v, float* __restrict__ out,
                                              const float* __restrict__ xin,
                                              const int* __restrict__ rowptr, const int* __restrict__ col,
                                              const float* __restrict__ wcs, int S) {
  unsigned bid = swz8(blockIdx.x, gridDim.x);
  long tid = (long)bid * 256 + threadIdx.x;
  long ng = tid / LPN;
  int c = (int)(tid % LPN);
  if (ng >= (long)S * NN) return;
  int s = (int)(ng / NN);
  int n = (int)(ng % NN);
  if constexpr (LPN == 64) {
    n = __builtin_amdgcn_readfirstlane(n);
    s = __builtin_amdgcn_readfirstlane(s);
  }
  if (c < C) {
    int beg = rowptr[n], end = rowptr[n + 1];
    const float* vs = v + (long)s * NN * C;
    float acc = 0.f;
    for (int e = beg; e < end; ++e)
      acc = fmaf(wcs[e], vs[(long)col[e] * C + c], acc);
    long oi = ((long)s * NN + n) * C + c;
    out[oi] = xin ? (2.f * acc - xin[oi]) : acc;
  }
}

// ---------------- Cheb combine ----------------
__global__ void __launch_bounds__(256) k_cheb_combine(const float4* X4,
                                                      const float4* __restrict__ T14,
                                                      const float4* __restrict__ T24,
                                                      const float* __restrict__ W,
                                                      const float* __restrict__ Bv,
                                                      float* out, long rows) {
  long row = (long)blockIdx.x * 256 + threadIdx.x;
  if (row >= rows) return;
  float acc[64];
#pragma unroll
  for (int j = 0; j < 64; ++j) acc[j] = Bv[j];
#pragma unroll
  for (int k = 0; k < 3; ++k) {
    const float4* src = (k == 0) ? X4 : (k == 1) ? T14 : T24;
    const float* Wk = W + k * 4096;
    for (int c4 = 0; c4 < 16; ++c4) {
      float4 vv = src[row * 16 + c4];
      const float* w0 = Wk + (c4 * 4) * 64;
#pragma unroll
      for (int j = 0; j < 64; ++j)
        acc[j] += vv.x * w0[j] + vv.y * w0[64 + j] + vv.z * w0[128 + j] + vv.w * w0[192 + j];
    }
  }
  float4* o4 = (float4*)(out + row * 64);
#pragma unroll
  for (int j = 0; j < 16; ++j)
    o4[j] = make_float4(fmaxf(acc[4 * j], 0.f), fmaxf(acc[4 * j + 1], 0.f),
                        fmaxf(acc[4 * j + 2], 0.f), fmaxf(acc[4 * j + 3], 0.f));
}

// ---------------- temporal conv 2 ----------------
__global__ void __launch_bounds__(256) k_tc2(const float4* __restrict__ h2, const float* __restrict__ W,
                                             const float* __restrict__ Bv, float* __restrict__ h3, int b) {
  long tid = (long)blockIdx.x * 256 + threadIdx.x;
  if (tid >= (long)T2n * NN) return;
  int t2 = (int)(tid / NN), n = (int)(tid % NN);
  float p[5], q[5], r[5];
#pragma unroll
  for (int co = 0; co < 5; ++co) { p[co] = Bv[co]; q[co] = Bv[5 + co]; r[co] = Bv[10 + co]; }
#pragma unroll
  for (int k = 0; k < 3; ++k) {
    const float4* rowp = h2 + ((long)(t2 + k) * NN + n) * 16;
    for (int c4 = 0; c4 < 16; ++c4) {
      float4 vv = rowp[c4];
      const float* w = W + ((k * 64) + c4 * 4) * 5;
#pragma unroll
      for (int co = 0; co < 5; ++co) {
        p[co] += vv.x * w[co]        + vv.y * w[5 + co]    + vv.z * w[10 + co]   + vv.w * w[15 + co];
        q[co] += vv.x * w[960 + co]  + vv.y * w[965 + co]  + vv.z * w[970 + co]  + vv.w * w[975 + co];
        r[co] += vv.x * w[1920 + co] + vv.y * w[1925 + co] + vv.z * w[1930 + co] + vv.w * w[1935 + co];
      }
    }
  }
#pragma unroll
  for (int co = 0; co < 5; ++co) {
    float sq = 1.f / (1.f + expf(-q[co]));
    h3[((long)(t2 * 4 + b) * NN + n) * 5 + co] = fmaxf(p[co] * sq + r[co], 0.f);
  }
}

// ---------------- BatchNorm ----------------
__global__ void __launch_bounds__(256) k_bn_stats(const float* __restrict__ h3,
                                                  const float* __restrict__ gamma,
                                                  const float* __restrict__ beta,
                                                  float* __restrict__ bnS, float* __restrict__ bnH) {
  long tid = (long)blockIdx.x * 256 + threadIdx.x;
  if (tid >= 4L * NN) return;
  int q = (int)(tid & 3);
  int n = (int)(tid >> 2);
  float s1 = 0.f, s2 = 0.f;
  for (int t = q * 2; t < q * 2 + 2; ++t)
    for (int b = 0; b < 4; ++b) {
      const float* p = h3 + ((long)(t * 4 + b) * NN + n) * 5;
#pragma unroll
      for (int co = 0; co < 5; ++co) { float v = p[co]; s1 += v; s2 += v * v; }
    }
  s1 += __shfl_xor(s1, 1, 4); s1 += __shfl_xor(s1, 2, 4);
  s2 += __shfl_xor(s2, 1, 4); s2 += __shfl_xor(s2, 2, 4);
  if (q == 0) {
    float mean = s1 * (1.f / 160.f);
    float var = s2 * (1.f / 160.f) - mean * mean;
    float sc = gamma[n] * rsqrtf(var + 1e-5f);
    bnS[n] = sc;
    bnH[n] = beta[n] - mean * sc;
  }
}

__global__ void __launch_bounds__(256) k_bn_apply(float* __restrict__ h3,
                                                  const float* __restrict__ bnS,
                                                  const float* __restrict__ bnH) {
  long tid = (long)blockIdx.x * 256 + threadIdx.x;
  if (tid >= 32L * NN * 5) return;
  int n = (int)((tid / 5) % NN);
  h3[tid] = fmaxf(h3[tid] * bnS[n] + bnH[n], 0.f);
}

// ---------------- fused GRU step kernels ----------------
// 32 lanes per (b,n) node; weights in LDS; h-row matvec via __shfl broadcast;
// CSR prop gathered inline (no separate prop kernel, no PH/PHR buffers).
__global__ void __launch_bounds__(256) k_gru1(const float* __restrict__ h3, const float* __restrict__ PX,
                                              const float* __restrict__ Hp,
                                              const int* __restrict__ rowptr, const int* __restrict__ col,
                                              const float* __restrict__ wcs,
                                              const float* __restrict__ gwx, const float* __restrict__ gbx,
                                              const float* __restrict__ gwh, const float* __restrict__ gbh,
                                              float* __restrict__ Z, float* __restrict__ HR, int t) {
  __shared__ float swh[4096];  // whz0 | whz1 | whr0 | whr1 (each 32x32)
  __shared__ float swx[640];   // wxz0 | wxz1 | wxr0 | wxr1 (each 5x32)
  for (int i = threadIdx.x; i < 4096; i += 256) swh[i] = gwh[i];
  for (int i = threadIdx.x; i < 640; i += 256) swx[i] = gwx[i];
  __syncthreads();
  unsigned bid = swz8(blockIdx.x, gridDim.x);
  long tid = (long)bid * 256 + threadIdx.x;
  long ng = tid >> 5;
  int j = (int)(tid & 31);
  if (ng >= 4L * NN) return;
  int b = (int)(ng / NN), n = (int)(ng % NN);
  long hrow = ng * 32;
  long xrow = ((long)(t * 4 + b) * NN + n) * 5;
  const float* hsrc = Hp + (long)b * NN * 32;
  float hv = Hp[hrow + j];
  float ph = 0.f;
  int beg = rowptr[n], end = rowptr[n + 1];
  for (int e = beg; e < end; ++e)
    ph = fmaf(wcs[e], hsrc[(long)col[e] * 32 + j], ph);
  float az = gbx[j] + gbh[j];
  float ar = gbx[32 + j] + gbh[32 + j];
#pragma unroll
  for (int ci = 0; ci < 5; ++ci) {
    float xv = h3[xrow + ci], pv = PX[xrow + ci];
    az += xv * swx[ci * 32 + j] + pv * swx[160 + ci * 32 + j];
    ar += xv * swx[320 + ci * 32 + j] + pv * swx[480 + ci * 32 + j];
  }
#pragma unroll
  for (int ci = 0; ci < 32; ++ci) {
    float hb = __shfl(hv, ci, 32);
    float pb = __shfl(ph, ci, 32);
    az += hb * swh[ci * 32 + j] + pb * swh[1024 + ci * 32 + j];
    ar += hb * swh[2048 + ci * 32 + j] + pb * swh[3072 + ci * 32 + j];
  }
  float zz = 1.f / (1.f + expf(-az));
  float rr = 1.f / (1.f + expf(-ar));
  Z[hrow + j] = zz;
  HR[hrow + j] = hv * rr;
}

__global__ void __launch_bounds__(256) k_gru2(const float* __restrict__ h3, const float* __restrict__ PX,
                                              const float* __restrict__ Hp, const float* __restrict__ Z,
                                              const float* __restrict__ HR,
                                              const int* __restrict__ rowptr, const int* __restrict__ col,
                                              const float* __restrict__ wcs,
                                              const float* __restrict__ gwx, const float* __restrict__ gbx,
                                              const float* __restrict__ gwh, const float* __restrict__ gbh,
                                              const float* __restrict__ lw, const float* __restrict__ lb,
                                              float* __restrict__ Hn, float* __restrict__ logits, int t) {
  __shared__ float swh[2048];  // whh0 | whh1
  __shared__ float swx[320];   // wxh0 | wxh1
  for (int i = threadIdx.x; i < 2048; i += 256) swh[i] = gwh[4096 + i];
  for (int i = threadIdx.x; i < 320; i += 256) swx[i] = gwx[640 + i];
  __syncthreads();
  unsigned bid = swz8(blockIdx.x, gridDim.x);
  long tid = (long)bid * 256 + threadIdx.x;
  long ng = tid >> 5;
  int j = (int)(tid & 31);
  if (ng >= 4L * NN) return;
  int b = (int)(ng / NN), n = (int)(ng % NN);
  long hrow = ng * 32;
  long xrow = ((long)(t * 4 + b) * NN + n) * 5;
  const float* hsrc = HR + (long)b * NN * 32;
  float hrv = HR[hrow + j];
  float phr = 0.f;
  int beg = rowptr[n], end = rowptr[n + 1];
  for (int e = beg; e < end; ++e)
    phr = fmaf(wcs[e], hsrc[(long)col[e] * 32 + j], phr);
  float a = gbx[64 + j] + gbh[64 + j];
#pragma unroll
  for (int ci = 0; ci < 5; ++ci) {
    float xv = h3[xrow + ci], pv = PX[xrow + ci];
    a += xv * swx[ci * 32 + j] + pv * swx[160 + ci * 32 + j];
  }
#pragma unroll
  for (int ci = 0; ci < 32; ++ci) {
    float hb = __shfl(hrv, ci, 32);
    float pb = __shfl(phr, ci, 32);
    a += hb * swh[ci * 32 + j] + pb * swh[1024 + ci * 32 + j];
  }
  float zz = Z[hrow + j];
  float hn = zz * Hp[hrow + j] + (1.f - zz) * tanhf(a);
  Hn[hrow + j] = hn;
  float c = fmaxf(hn, 0.f) * lw[j];
  c += __shfl_xor(c, 16, 32);
  c += __shfl_xor(c, 8, 32);
  c += __shfl_xor(c, 4, 32);
  c += __shfl_xor(c, 2, 32);
  c += __shfl_xor(c, 1, 32);
  if (j == 0) logits[((long)b * 8 + t) * NN + n] = c + lb[0];
}

// ---------------- final log_softmax over the 8 time steps ----------------
__global__ void __launch_bounds__(256) k_logsoftmax(const float* __restrict__ logits, float* __restrict__ out) {
  long tid = (long)blockIdx.x * 256 + threadIdx.x;
  if (tid >= 4L * NN) return;
  int b = (int)(tid / NN), n = (int)(tid % NN);
  float l[8];
#pragma unroll
  for (int t = 0; t < 8; ++t) l[t] = logits[((long)b * 8 + t) * NN + n];
  float m = l[0];
#pragma unroll
  for (int t = 1; t < 8; ++t) m = fmaxf(m, l[t]);
  float s = 0.f;
#pragma unroll
  for (int t = 0; t < 8; ++t) s += expf(l[t] - m);
  float lse = m + logf(s);
#pragma unroll
  for (int t = 0; t < 8; ++t) out[((long)b * 8 + t) * NN + n] = l[t] - lse;
}

// ---------------- host orchestration ----------------
extern "C" void kernel_launch(void* const* d_in, const int* in_sizes, int n_in,
                              void* d_out, int out_size, void* d_ws, size_t ws_size,
                              hipStream_t stream) {
  const float* x     = (const float*)d_in[0];
  const int*   ei    = (const int*)d_in[1];
  const float* tc1w  = (const float*)d_in[2];
  const float* tc1b  = (const float*)d_in[3];
  const float* chebw = (const float*)d_in[4];
  const float* chebb = (const float*)d_in[5];
  const float* tc2w  = (const float*)d_in[6];
  const float* tc2b  = (const float*)d_in[7];
  const float* gam   = (const float*)d_in[8];
  const float* bet   = (const float*)d_in[9];
  const float* gwx   = (const float*)d_in[10];
  const float* gbx   = (const float*)d_in[11];
  const float* gwh   = (const float*)d_in[12];
  const float* gbh   = (const float*)d_in[13];
  const float* lw    = (const float*)d_in[14];
  const float* lb    = (const float*)d_in[15];
  float* out = (float*)d_out;
  int E = in_sizes[1] / 2;
  if (ws_size < WS_NEED) return;

  char* ws = (char*)d_ws;
  float* X    = (float*)(ws + O_X);
  float* Tb1  = (float*)(ws + O_T1);
  float* Tb2  = (float*)(ws + O_T2);
  float* h3   = (float*)(ws + O_H3);
  float* PX   = (float*)(ws + O_PX);
  float* bnS  = (float*)(ws + O_BNS);
  float* bnH  = (float*)(ws + O_BNH);
  float* degf = (float*)(ws + O_DEG);
  int*   ind  = (int*)(ws + O_IND);
  int*   cur  = (int*)(ws + O_CUR);
  float* dnv  = (float*)(ws + O_DNV);
  int*   rp   = (int*)(ws + O_RP);
  int*   col  = (int*)(ws + O_COL);
  float* wcs  = (float*)(ws + O_WCS);
  float* lg   = (float*)(ws + O_LG);
  // GRU buffers reuse the X region (free after the per-b pipeline)
  float* Hp  = (float*)(ws + O_X);
  float* Hn  = (float*)(ws + O_X + SZ_H);
  float* Zb  = (float*)(ws + O_X + 2 * SZ_H);
  float* HRb = (float*)(ws + O_X + 3 * SZ_H);

  // --- graph prep ---
  hipMemsetAsync(ws + O_DEG, 0, 240000, stream);  // degf, indeg, cursor
  unsigned gE = (unsigned)((E + 255) / 256);
  k_edge_count<<<gE, 256, 0, stream>>>(ei, E, degf, ind);
  k_dinv<<<(NN + 255) / 256, 256, 0, stream>>>(degf, dnv);
  k_scan<<<1, 1024, 0, stream>>>(ind, rp);
  k_fill<<<gE, 256, 0, stream>>>(ei, E, dnv, rp, cur, col, wcs);

  // --- per-batch STConv pipeline ---
  const long nTh64 = (long)T1n * NN * 64;
  unsigned g64 = (unsigned)((nTh64 + 255) / 256);  // 50000 (exact)
  for (int b = 0; b < 4; ++b) {
    k_tc1<<<g64, 256, 0, stream>>>(x, tc1w, tc1b, X, b);
    k_prop<64, 64><<<g64, 256, 0, stream>>>(X, Tb1, nullptr, rp, col, wcs, T1n);
    k_prop<64, 64><<<g64, 256, 0, stream>>>(Tb1, Tb2, X, rp, col, wcs, T1n);
    k_cheb_combine<<<(unsigned)(((long)T1n * NN + 255) / 256), 256, 0, stream>>>(
        (const float4*)X, (const float4*)Tb1, (const float4*)Tb2, chebw, chebb, X, (long)T1n * NN);
    k_tc2<<<(unsigned)(((long)T2n * NN + 255) / 256), 256, 0, stream>>>(
        (const float4*)X, tc2w, tc2b, h3, b);
  }

  // --- BatchNorm (per node) + relu ---
  k_bn_stats<<<(4 * NN + 255) / 256, 256, 0, stream>>>(h3, gam, bet, bnS, bnH);
  k_bn_apply<<<(unsigned)((32L * NN * 5 + 255) / 256), 256, 0, stream>>>(h3, bnS, bnH);

  // --- precompute prop(Xt) for all 32 (t,b) slices ---
  k_prop<5, 8><<<(unsigned)((32L * NN * 8 + 255) / 256), 256, 0, stream>>>(
      h3, PX, nullptr, rp, col, wcs, 32);

  // --- GConvGRU, 8 sequential steps (2 fused kernels each) ---
  hipMemsetAsync(Hp, 0, SZ_H, stream);
  float* hp = Hp;
  float* hn = Hn;
  unsigned gG = (unsigned)((4L * NN * 32 + 255) / 256);  // 10000 (exact)
  for (int t = 0; t < 8; ++t) {
    k_gru1<<<gG, 256, 0, stream>>>(h3, PX, hp, rp, col, wcs, gwx, gbx, gwh, gbh, Zb, HRb, t);
    k_gru2<<<gG, 256, 0, stream>>>(h3, PX, hp, Zb, HRb, rp, col, wcs, gwx, gbx, gwh, gbh,
                                   lw, lb, hn, lg, t);
    float* tmp = hp; hp = hn; hn = tmp;
  }

  unsigned gN = (unsigned)((4L * NN + 255) / 256);
  k_logsoftmax<<<gN, 256, 0, stream>>>(lg, out);
}

// Round 3
// 3287.409 us; speedup vs baseline: 1.4184x; 1.2008x over previous
//
#include <hip/hip_runtime.h>

constexpr int BB = 4, TT = 12, NN = 20000, FIN = 2;
constexpr int HID = 64, OUTC = 5;
constexpr int FIL = 32;
constexpr int T1n = 10, T2n = 8;
constexpr long ROWS = (long)T1n * NN;  // 200000 rows per batch

typedef __attribute__((ext_vector_type(8))) short short8v;  // 8 bf16 (4 VGPRs)
typedef __attribute__((ext_vector_type(4))) float f32x4;

// ---------------- workspace layout (bytes) ----------------
constexpr size_t SZ_B   = (size_t)ROWS * 64 * 2;   // 25,600,000 bf16 slab
constexpr size_t SZ_H2  = (size_t)ROWS * 64 * 4;   // 51,200,000 fp32
constexpr size_t SZ_H3  = (size_t)T2n * BB * NN * OUTC * 4;  // 12,800,000
constexpr size_t O_XB  = 0;
constexpr size_t O_T1B = SZ_B;
constexpr size_t O_T2B = 2 * SZ_B;
constexpr size_t O_H2  = 3 * SZ_B;
constexpr size_t O_H3  = O_H2 + SZ_H2;
constexpr size_t O_PX  = O_H3 + SZ_H3;
constexpr size_t O_BNS = O_PX + SZ_H3;
constexpr size_t O_BNH = O_BNS + 80000;
constexpr size_t O_DEG = O_BNH + 80000;
constexpr size_t O_IND = O_DEG + 80000;
constexpr size_t O_CUR = O_IND + 80000;
constexpr size_t O_DNV = O_CUR + 80000;
constexpr size_t O_RP  = O_DNV + 80000;
constexpr size_t O_COL = O_RP + 80128;
constexpr size_t O_WCS = O_COL + 1280000;
constexpr size_t O_LG  = O_WCS + 1280000;
constexpr size_t O_WP  = O_LG + 2560000;           // packed cheb weights, 24,576 B
constexpr size_t WS_NEED = O_WP + 24576;
constexpr size_t SZ_H = (size_t)BB * NN * FIL * 4; // 10,240,000 (GRU state)

// ---------------- bf16 helpers ----------------
__device__ __forceinline__ float bf2f(unsigned short u) {
  union { unsigned i; float f; } x; x.i = ((unsigned)u) << 16; return x.f;
}
__device__ __forceinline__ unsigned short f2bf(float f) {
  union { float f; unsigned i; } x; x.f = f;
  unsigned r = x.i + 0x7FFFu + ((x.i >> 16) & 1u);
  return (unsigned short)(r >> 16);
}

// ---------------- XCD-chunked bijective block swizzle (m204) ----------------
__device__ __forceinline__ unsigned swz8(unsigned orig, unsigned nwg) {
  unsigned q = nwg >> 3, r = nwg & 7;
  unsigned xcd = orig & 7, off = orig >> 3;
  unsigned base = (xcd < r) ? xcd * (q + 1) : r * (q + 1) + (xcd - r) * q;
  return base + off;
}

// ---------------- graph preprocessing ----------------
__global__ void __launch_bounds__(256) k_edge_count(const int* __restrict__ ei, int E,
                                                    float* __restrict__ degf, int* __restrict__ indeg) {
  int e = blockIdx.x * 256 + threadIdx.x;
  if (e >= E) return;
  int s = ei[e], d = ei[E + e];
  if (s != d) {
    atomicAdd(&degf[s], 1.0f);
    atomicAdd(&indeg[d], 1);
  }
}

__global__ void __launch_bounds__(256) k_dinv(const float* __restrict__ degf, float* __restrict__ dinv) {
  int n = blockIdx.x * 256 + threadIdx.x;
  if (n >= NN) return;
  float d = degf[n];
  dinv[n] = d > 0.f ? rsqrtf(d) : 0.f;
}

__global__ void __launch_bounds__(1024) k_scan(const int* __restrict__ indeg, int* __restrict__ rowptr) {
  __shared__ int part[1024];
  const int chunk = (NN + 1023) / 1024;
  int t = threadIdx.x;
  int beg = t * chunk, end = min(beg + chunk, NN);
  int s = 0;
  for (int i = beg; i < end; ++i) s += indeg[i];
  part[t] = s;
  __syncthreads();
  if (t == 0) {
    int run = 0;
    for (int i = 0; i < 1024; ++i) { int v = part[i]; part[i] = run; run += v; }
    rowptr[NN] = run;
  }
  __syncthreads();
  int run = part[t];
  for (int i = beg; i < end; ++i) { rowptr[i] = run; run += indeg[i]; }
}

__global__ void __launch_bounds__(256) k_fill(const int* __restrict__ ei, int E,
                                              const float* __restrict__ dinv,
                                              const int* __restrict__ rowptr,
                                              int* __restrict__ cursor,
                                              int* __restrict__ col, float* __restrict__ wcs) {
  int e = blockIdx.x * 256 + threadIdx.x;
  if (e >= E) return;
  int s = ei[e], d = ei[E + e];
  if (s != d) {
    int p = atomicAdd(&cursor[d], 1);
    int o = rowptr[d] + p;
    col[o] = s;
    wcs[o] = -dinv[s] * dinv[d];
  }
}

// ---------------- cheb weight pack into MFMA B-fragment order (bf16) ----------------
// frag f = kk*4+jt (kk: K-chunk of 32 over [T0|T1|T2] concat, jt: 16-col tile)
// lane l elem e: B[k][n] with k = 8*(l>>4)+e (within chunk), n = jt*16 + (l&15)
__global__ void __launch_bounds__(256) k_wpack(const float* __restrict__ W, unsigned short* __restrict__ Wp) {
  int id = blockIdx.x * 256 + threadIdx.x;  // 6 blocks * 256 = 1536 = 24 frags * 64 lanes
  int f = id >> 6, l = id & 63;
  int kk = f >> 2, jt = f & 3;
  int kcheb = kk >> 1;
  int cout = jt * 16 + (l & 15);
#pragma unroll
  for (int e = 0; e < 8; ++e) {
    int cin = (kk & 1) * 32 + (l >> 4) * 8 + e;
    Wp[(size_t)f * 512 + l * 8 + e] = f2bf(W[(size_t)kcheb * 4096 + cin * 64 + cout]);
  }
}

// ---------------- temporal conv 1: (B,T,N,2) -> per-b bf16 (10,N,64) ----------------
__global__ void __launch_bounds__(256) k_tc1(const float* __restrict__ x, const float* __restrict__ W,
                                             const float* __restrict__ Bv, unsigned short* __restrict__ out, int b) {
  __shared__ float ws[1152];
  __shared__ float bs[192];
  for (int i = threadIdx.x; i < 1152; i += 256) ws[i] = W[i];
  for (int i = threadIdx.x; i < 192; i += 256) bs[i] = Bv[i];
  __syncthreads();
  long tid = (long)blockIdx.x * 256 + threadIdx.x;
  if (tid >= ROWS * 64) return;
  int co = (int)(tid & 63);
  int n  = (int)((tid >> 6) % NN);
  int to = (int)(tid / (64L * NN));
  float aP = bs[co], aQ = bs[64 + co], aR = bs[128 + co];
#pragma unroll
  for (int k = 0; k < 3; ++k) {
#pragma unroll
    for (int ci = 0; ci < 2; ++ci) {
      float xv = x[(((long)b * TT + to + k) * NN + n) * FIN + ci];
      int wi = (k * 2 + ci) * 64 + co;
      aP = fmaf(xv, ws[wi], aP);
      aQ = fmaf(xv, ws[384 + wi], aQ);
      aR = fmaf(xv, ws[768 + wi], aR);
    }
  }
  float sq = 1.f / (1.f + expf(-aQ));
  out[tid] = f2bf(fmaxf(aP * sq + aR, 0.f));
}

// ---------------- bf16 CSR propagation (64 ch/node, XCD-swizzled) ----------------
// out = prop(v); if xin: out = 2*prop(v) - xin   (Chebyshev)
__global__ void __launch_bounds__(256) k_prop_bf(const unsigned short* __restrict__ v,
                                                 unsigned short* __restrict__ out,
                                                 const unsigned short* __restrict__ xin,
                                                 const int* __restrict__ rowptr, const int* __restrict__ col,
                                                 const float* __restrict__ wcs) {
  unsigned bid = swz8(blockIdx.x, gridDim.x);
  long tid = (long)bid * 256 + threadIdx.x;
  long ng = tid >> 6;
  int c = (int)(tid & 63);
  if (ng >= ROWS) return;
  int s = (int)(ng / NN);
  int n = (int)(ng % NN);
  n = __builtin_amdgcn_readfirstlane(n);
  s = __builtin_amdgcn_readfirstlane(s);
  int beg = rowptr[n], end = rowptr[n + 1];
  const unsigned short* vs = v + (long)s * NN * 64;
  float acc = 0.f;
  for (int e = beg; e < end; ++e)
    acc = fmaf(wcs[e], bf2f(vs[(long)col[e] * 64 + c]), acc);
  long oi = ng * 64 + c;
  out[oi] = f2bf(xin ? (2.f * acc - bf2f(xin[oi])) : acc);
}

// ---------------- Cheb combine via MFMA: H2 = relu([T0|T1|T2]bf16 @ Wbf16 + b) ----------------
__global__ void __launch_bounds__(256) k_cheb_mfma(const unsigned short* __restrict__ Xb,
                                                   const unsigned short* __restrict__ T1b,
                                                   const unsigned short* __restrict__ T2b,
                                                   const unsigned short* __restrict__ Wp,
                                                   const float* __restrict__ Bv,
                                                   float* __restrict__ H2) {
  int wid = threadIdx.x >> 6, lane = threadIdx.x & 63;
  long tile = (long)blockIdx.x * 4 + wid;          // 12500 tiles of 16 rows
  if (tile >= ROWS / 16) return;
  int r = lane & 15, g = lane >> 4;
  // weight frags (all 24) — L1-broadcast loads
  short8v wf[24];
#pragma unroll
  for (int f = 0; f < 24; ++f)
    wf[f] = *(const short8v*)(Wp + (size_t)f * 512 + lane * 8);
  float bias[4];
#pragma unroll
  for (int jt = 0; jt < 4; ++jt) bias[jt] = Bv[jt * 16 + r];
  long rowbase = tile * 16;
  f32x4 acc[4];
#pragma unroll
  for (int jt = 0; jt < 4; ++jt) acc[jt] = (f32x4){0.f, 0.f, 0.f, 0.f};
  const unsigned short* srcs[3] = {Xb, T1b, T2b};
#pragma unroll
  for (int kk = 0; kk < 6; ++kk) {
    const unsigned short* S = srcs[kk >> 1];
    short8v a = *(const short8v*)(S + (rowbase + r) * 64 + (kk & 1) * 32 + g * 8);
#pragma unroll
    for (int jt = 0; jt < 4; ++jt)
      acc[jt] = __builtin_amdgcn_mfma_f32_16x16x32_bf16(a, wf[kk * 4 + jt], acc[jt], 0, 0, 0);
  }
#pragma unroll
  for (int jt = 0; jt < 4; ++jt)
#pragma unroll
    for (int reg = 0; reg < 4; ++reg) {
      int m = 4 * g + reg;
      H2[(rowbase + m) * 64 + jt * 16 + r] = fmaxf(acc[jt][reg] + bias[jt], 0.f);
    }
}

// ---------------- generic fp32 CSR propagation (for PX precompute) ----------------
template <int C, int LPN>
__global__ void __launch_bounds__(256) k_prop(const float* __restrict__ v, float* __restrict__ out,
                                              const int* __restrict__ rowptr, const int* __restrict__ col,
                                              const float* __restrict__ wcs, int S) {
  unsigned bid = swz8(blockIdx.x, gridDim.x);
  long tid = (long)bid * 256 + threadIdx.x;
  long ng = tid / LPN;
  int c = (int)(tid % LPN);
  if (ng >= (long)S * NN) return;
  int s = (int)(ng / NN);
  int n = (int)(ng % NN);
  if (c < C) {
    int beg = rowptr[n], end = rowptr[n + 1];
    const float* vs = v + (long)s * NN * C;
    float acc = 0.f;
    for (int e = beg; e < end; ++e)
      acc = fmaf(wcs[e], vs[(long)col[e] * C + c], acc);
    out[((long)s * NN + n) * C + c] = acc;
  }
}

// ---------------- temporal conv 2: per-b (10,N,64) -> h3[t][b][n][5] ----------------
__global__ void __launch_bounds__(256) k_tc2(const float4* __restrict__ h2, const float* __restrict__ W,
                                             const float* __restrict__ Bv, float* __restrict__ h3, int b) {
  long tid = (long)blockIdx.x * 256 + threadIdx.x;
  if (tid >= (long)T2n * NN) return;
  int t2 = (int)(tid / NN), n = (int)(tid % NN);
  float p[5], q[5], r[5];
#pragma unroll
  for (int co = 0; co < 5; ++co) { p[co] = Bv[co]; q[co] = Bv[5 + co]; r[co] = Bv[10 + co]; }
#pragma unroll
  for (int k = 0; k < 3; ++k) {
    const float4* rowp = h2 + ((long)(t2 + k) * NN + n) * 16;
    for (int c4 = 0; c4 < 16; ++c4) {
      float4 vv = rowp[c4];
      const float* w = W + ((k * 64) + c4 * 4) * 5;
#pragma unroll
      for (int co = 0; co < 5; ++co) {
        p[co] += vv.x * w[co]        + vv.y * w[5 + co]    + vv.z * w[10 + co]   + vv.w * w[15 + co];
        q[co] += vv.x * w[960 + co]  + vv.y * w[965 + co]  + vv.z * w[970 + co]  + vv.w * w[975 + co];
        r[co] += vv.x * w[1920 + co] + vv.y * w[1925 + co] + vv.z * w[1930 + co] + vv.w * w[1935 + co];
      }
    }
  }
#pragma unroll
  for (int co = 0; co < 5; ++co) {
    float sq = 1.f / (1.f + expf(-q[co]));
    h3[((long)(t2 * 4 + b) * NN + n) * 5 + co] = fmaxf(p[co] * sq + r[co], 0.f);
  }
}

// ---------------- BatchNorm ----------------
__global__ void __launch_bounds__(256) k_bn_stats(const float* __restrict__ h3,
                                                  const float* __restrict__ gamma,
                                                  const float* __restrict__ beta,
                                                  float* __restrict__ bnS, float* __restrict__ bnH) {
  long tid = (long)blockIdx.x * 256 + threadIdx.x;
  if (tid >= 4L * NN) return;
  int q = (int)(tid & 3);
  int n = (int)(tid >> 2);
  float s1 = 0.f, s2 = 0.f;
  for (int t = q * 2; t < q * 2 + 2; ++t)
    for (int b = 0; b < 4; ++b) {
      const float* p = h3 + ((long)(t * 4 + b) * NN + n) * 5;
#pragma unroll
      for (int co = 0; co < 5; ++co) { float v = p[co]; s1 += v; s2 += v * v; }
    }
  s1 += __shfl_xor(s1, 1, 4); s1 += __shfl_xor(s1, 2, 4);
  s2 += __shfl_xor(s2, 1, 4); s2 += __shfl_xor(s2, 2, 4);
  if (q == 0) {
    float mean = s1 * (1.f / 160.f);
    float var = s2 * (1.f / 160.f) - mean * mean;
    float sc = gamma[n] * rsqrtf(var + 1e-5f);
    bnS[n] = sc;
    bnH[n] = beta[n] - mean * sc;
  }
}

__global__ void __launch_bounds__(256) k_bn_apply(float* __restrict__ h3,
                                                  const float* __restrict__ bnS,
                                                  const float* __restrict__ bnH) {
  long tid = (long)blockIdx.x * 256 + threadIdx.x;
  if (tid >= 32L * NN * 5) return;
  int n = (int)((tid / 5) % NN);
  h3[tid] = fmaxf(h3[tid] * bnS[n] + bnH[n], 0.f);
}

// ---------------- fused GRU step kernels (unchanged from R2 — proven) ----------------
__global__ void __launch_bounds__(256) k_gru1(const float* __restrict__ h3, const float* __restrict__ PX,
                                              const float* __restrict__ Hp,
                                              const int* __restrict__ rowptr, const int* __restrict__ col,
                                              const float* __restrict__ wcs,
                                              const float* __restrict__ gwx, const float* __restrict__ gbx,
                                              const float* __restrict__ gwh, const float* __restrict__ gbh,
                                              float* __restrict__ Z, float* __restrict__ HR, int t) {
  __shared__ float swh[4096];
  __shared__ float swx[640];
  for (int i = threadIdx.x; i < 4096; i += 256) swh[i] = gwh[i];
  for (int i = threadIdx.x; i < 640; i += 256) swx[i] = gwx[i];
  __syncthreads();
  unsigned bid = swz8(blockIdx.x, gridDim.x);
  long tid = (long)bid * 256 + threadIdx.x;
  long ng = tid >> 5;
  int j = (int)(tid & 31);
  if (ng >= 4L * NN) return;
  int b = (int)(ng / NN), n = (int)(ng % NN);
  long hrow = ng * 32;
  long xrow = ((long)(t * 4 + b) * NN + n) * 5;
  const float* hsrc = Hp + (long)b * NN * 32;
  float hv = Hp[hrow + j];
  float ph = 0.f;
  int beg = rowptr[n], end = rowptr[n + 1];
  for (int e = beg; e < end; ++e)
    ph = fmaf(wcs[e], hsrc[(long)col[e] * 32 + j], ph);
  float az = gbx[j] + gbh[j];
  float ar = gbx[32 + j] + gbh[32 + j];
#pragma unroll
  for (int ci = 0; ci < 5; ++ci) {
    float xv = h3[xrow + ci], pv = PX[xrow + ci];
    az += xv * swx[ci * 32 + j] + pv * swx[160 + ci * 32 + j];
    ar += xv * swx[320 + ci * 32 + j] + pv * swx[480 + ci * 32 + j];
  }
#pragma unroll
  for (int ci = 0; ci < 32; ++ci) {
    float hb = __shfl(hv, ci, 32);
    float pb = __shfl(ph, ci, 32);
    az += hb * swh[ci * 32 + j] + pb * swh[1024 + ci * 32 + j];
    ar += hb * swh[2048 + ci * 32 + j] + pb * swh[3072 + ci * 32 + j];
  }
  float zz = 1.f / (1.f + expf(-az));
  float rr = 1.f / (1.f + expf(-ar));
  Z[hrow + j] = zz;
  HR[hrow + j] = hv * rr;
}

__global__ void __launch_bounds__(256) k_gru2(const float* __restrict__ h3, const float* __restrict__ PX,
                                              const float* __restrict__ Hp, const float* __restrict__ Z,
                                              const float* __restrict__ HR,
                                              const int* __restrict__ rowptr, const int* __restrict__ col,
                                              const float* __restrict__ wcs,
                                              const float* __restrict__ gwx, const float* __restrict__ gbx,
                                              const float* __restrict__ gwh, const float* __restrict__ gbh,
                                              const float* __restrict__ lw, const float* __restrict__ lb,
                                              float* __restrict__ Hn, float* __restrict__ logits, int t) {
  __shared__ float swh[2048];
  __shared__ float swx[320];
  for (int i = threadIdx.x; i < 2048; i += 256) swh[i] = gwh[4096 + i];
  for (int i = threadIdx.x; i < 320; i += 256) swx[i] = gwx[640 + i];
  __syncthreads();
  unsigned bid = swz8(blockIdx.x, gridDim.x);
  long tid = (long)bid * 256 + threadIdx.x;
  long ng = tid >> 5;
  int j = (int)(tid & 31);
  if (ng >= 4L * NN) return;
  int b = (int)(ng / NN), n = (int)(ng % NN);
  long hrow = ng * 32;
  long xrow = ((long)(t * 4 + b) * NN + n) * 5;
  const float* hsrc = HR + (long)b * NN * 32;
  float hrv = HR[hrow + j];
  float phr = 0.f;
  int beg = rowptr[n], end = rowptr[n + 1];
  for (int e = beg; e < end; ++e)
    phr = fmaf(wcs[e], hsrc[(long)col[e] * 32 + j], phr);
  float a = gbx[64 + j] + gbh[64 + j];
#pragma unroll
  for (int ci = 0; ci < 5; ++ci) {
    float xv = h3[xrow + ci], pv = PX[xrow + ci];
    a += xv * swx[ci * 32 + j] + pv * swx[160 + ci * 32 + j];
  }
#pragma unroll
  for (int ci = 0; ci < 32; ++ci) {
    float hb = __shfl(hrv, ci, 32);
    float pb = __shfl(phr, ci, 32);
    a += hb * swh[ci * 32 + j] + pb * swh[1024 + ci * 32 + j];
  }
  float zz = Z[hrow + j];
  float hn = zz * Hp[hrow + j] + (1.f - zz) * tanhf(a);
  Hn[hrow + j] = hn;
  float c = fmaxf(hn, 0.f) * lw[j];
  c += __shfl_xor(c, 16, 32);
  c += __shfl_xor(c, 8, 32);
  c += __shfl_xor(c, 4, 32);
  c += __shfl_xor(c, 2, 32);
  c += __shfl_xor(c, 1, 32);
  if (j == 0) logits[((long)b * 8 + t) * NN + n] = c + lb[0];
}

// ---------------- final log_softmax over the 8 time steps ----------------
__global__ void __launch_bounds__(256) k_logsoftmax(const float* __restrict__ logits, float* __restrict__ out) {
  long tid = (long)blockIdx.x * 256 + threadIdx.x;
  if (tid >= 4L * NN) return;
  int b = (int)(tid / NN), n = (int)(tid % NN);
  float l[8];
#pragma unroll
  for (int t = 0; t < 8; ++t) l[t] = logits[((long)b * 8 + t) * NN + n];
  float m = l[0];
#pragma unroll
  for (int t = 1; t < 8; ++t) m = fmaxf(m, l[t]);
  float s = 0.f;
#pragma unroll
  for (int t = 0; t < 8; ++t) s += expf(l[t] - m);
  float lse = m + logf(s);
#pragma unroll
  for (int t = 0; t < 8; ++t) out[((long)b * 8 + t) * NN + n] = l[t] - lse;
}

// ---------------- host orchestration ----------------
extern "C" void kernel_launch(void* const* d_in, const int* in_sizes, int n_in,
                              void* d_out, int out_size, void* d_ws, size_t ws_size,
                              hipStream_t stream) {
  const float* x     = (const float*)d_in[0];
  const int*   ei    = (const int*)d_in[1];
  const float* tc1w  = (const float*)d_in[2];
  const float* tc1b  = (const float*)d_in[3];
  const float* chebw = (const float*)d_in[4];
  const float* chebb = (const float*)d_in[5];
  const float* tc2w  = (const float*)d_in[6];
  const float* tc2b  = (const float*)d_in[7];
  const float* gam   = (const float*)d_in[8];
  const float* bet   = (const float*)d_in[9];
  const float* gwx   = (const float*)d_in[10];
  const float* gbx   = (const float*)d_in[11];
  const float* gwh   = (const float*)d_in[12];
  const float* gbh   = (const float*)d_in[13];
  const float* lw    = (const float*)d_in[14];
  const float* lb    = (const float*)d_in[15];
  float* out = (float*)d_out;
  int E = in_sizes[1] / 2;
  if (ws_size < WS_NEED) return;

  char* ws = (char*)d_ws;
  unsigned short* Xb  = (unsigned short*)(ws + O_XB);
  unsigned short* T1b = (unsigned short*)(ws + O_T1B);
  unsigned short* T2b = (unsigned short*)(ws + O_T2B);
  float* H2   = (float*)(ws + O_H2);
  float* h3   = (float*)(ws + O_H3);
  float* PX   = (float*)(ws + O_PX);
  float* bnS  = (float*)(ws + O_BNS);
  float* bnH  = (float*)(ws + O_BNH);
  float* degf = (float*)(ws + O_DEG);
  int*   ind  = (int*)(ws + O_IND);
  int*   cur  = (int*)(ws + O_CUR);
  float* dnv  = (float*)(ws + O_DNV);
  int*   rp   = (int*)(ws + O_RP);
  int*   col  = (int*)(ws + O_COL);
  float* wcs  = (float*)(ws + O_WCS);
  float* lg   = (float*)(ws + O_LG);
  unsigned short* Wp = (unsigned short*)(ws + O_WP);
  // GRU buffers reuse the Xb/T1b region (free after the per-b pipeline)
  float* Hp  = (float*)(ws + O_XB);
  float* Hn  = (float*)(ws + O_XB + SZ_H);
  float* Zb  = (float*)(ws + O_XB + 2 * SZ_H);
  float* HRb = (float*)(ws + O_XB + 3 * SZ_H);

  // --- graph prep + weight pack ---
  hipMemsetAsync(ws + O_DEG, 0, 240000, stream);
  unsigned gE = (unsigned)((E + 255) / 256);
  k_edge_count<<<gE, 256, 0, stream>>>(ei, E, degf, ind);
  k_dinv<<<(NN + 255) / 256, 256, 0, stream>>>(degf, dnv);
  k_scan<<<1, 1024, 0, stream>>>(ind, rp);
  k_fill<<<gE, 256, 0, stream>>>(ei, E, dnv, rp, cur, col, wcs);
  k_wpack<<<6, 256, 0, stream>>>(chebw, Wp);

  // --- per-batch STConv pipeline ---
  unsigned g64 = (unsigned)((ROWS * 64 + 255) / 256);  // 50000
  for (int b = 0; b < 4; ++b) {
    k_tc1<<<g64, 256, 0, stream>>>(x, tc1w, tc1b, Xb, b);
    k_prop_bf<<<g64, 256, 0, stream>>>(Xb, T1b, nullptr, rp, col, wcs);
    k_prop_bf<<<g64, 256, 0, stream>>>(T1b, T2b, Xb, rp, col, wcs);
    k_cheb_mfma<<<(unsigned)(ROWS / 16 / 4), 256, 0, stream>>>(Xb, T1b, T2b, Wp, chebb, H2);
    k_tc2<<<(unsigned)(((long)T2n * NN + 255) / 256), 256, 0, stream>>>(
        (const float4*)H2, tc2w, tc2b, h3, b);
  }

  // --- BatchNorm (per node) + relu ---
  k_bn_stats<<<(4 * NN + 255) / 256, 256, 0, stream>>>(h3, gam, bet, bnS, bnH);
  k_bn_apply<<<(unsigned)((32L * NN * 5 + 255) / 256), 256, 0, stream>>>(h3, bnS, bnH);

  // --- precompute prop(Xt) for all 32 (t,b) slices ---
  k_prop<5, 8><<<(unsigned)((32L * NN * 8 + 255) / 256), 256, 0, stream>>>(
      h3, PX, rp, col, wcs, 32);

  // --- GConvGRU, 8 sequential steps (2 fused kernels each) ---
  hipMemsetAsync(Hp, 0, SZ_H, stream);
  float* hp = Hp;
  float* hn = Hn;
  unsigned gG = (unsigned)((4L * NN * 32 + 255) / 256);  // 10000
  for (int t = 0; t < 8; ++t) {
    k_gru1<<<gG, 256, 0, stream>>>(h3, PX, hp, rp, col, wcs, gwx, gbx, gwh, gbh, Zb, HRb, t);
    k_gru2<<<gG, 256, 0, stream>>>(h3, PX, hp, Zb, HRb, rp, col, wcs, gwx, gbx, gwh, gbh,
                                   lw, lb, hn, lg, t);
    float* tmp = hp; hp = hn; hn = tmp;
  }

  unsigned gN = (unsigned)((4L * NN + 255) / 256);
  k_logsoftmax<<<gN, 256, 0, stream>>>(lg, out);
}

// Round 4
// 2419.324 us; speedup vs baseline: 1.9273x; 1.3588x over previous
//
#include <hip/hip_runtime.h>

constexpr int BB = 4, TT = 12, NN = 20000, FIN = 2;
constexpr int HID = 64, OUTC = 5;
constexpr int FIL = 32;
constexpr int T1n = 10, T2n = 8;
constexpr long ROWS = (long)T1n * NN;  // 200000 rows per batch

typedef __attribute__((ext_vector_type(8))) short short8v;  // 8 bf16 (4 VGPRs)
typedef __attribute__((ext_vector_type(4))) float f32x4;

// ---------------- workspace layout (bytes) ----------------
constexpr size_t SZ_B   = (size_t)ROWS * 64 * 2;             // 25,600,000 bf16 slab
constexpr size_t SZ_H2  = (size_t)ROWS * 64 * 4;             // 51,200,000 fp32
constexpr size_t SZ_H3P = (size_t)T2n * BB * NN * 8 * 4;     // 20,480,000 (rows padded 5->8)
constexpr size_t O_XB  = 0;
constexpr size_t O_T1B = SZ_B;
constexpr size_t O_T2B = 2 * SZ_B;
constexpr size_t O_H2  = 3 * SZ_B;
constexpr size_t O_H3  = O_H2 + SZ_H2;
constexpr size_t O_PX  = O_H3 + SZ_H3P;
constexpr size_t O_BNS = O_PX + SZ_H3P;
constexpr size_t O_BNH = O_BNS + 80000;
constexpr size_t O_DEG = O_BNH + 80000;
constexpr size_t O_IND = O_DEG + 80000;
constexpr size_t O_CUR = O_IND + 80000;
constexpr size_t O_DNV = O_CUR + 80000;
constexpr size_t O_RP  = O_DNV + 80000;
constexpr size_t O_COL = O_RP + 80128;
constexpr size_t O_WCS = O_COL + 1280000;
constexpr size_t O_LG  = O_WCS + 1280000;
constexpr size_t O_WP  = O_LG + 2560000;           // packed cheb weights
constexpr size_t WS_NEED = O_WP + 24576;
constexpr size_t SZ_H = (size_t)BB * NN * FIL * 4; // 10,240,000 (GRU state)

// ---------------- bf16 helpers ----------------
__device__ __forceinline__ float bf2f(unsigned short u) {
  union { unsigned i; float f; } x; x.i = ((unsigned)u) << 16; return x.f;
}
__device__ __forceinline__ unsigned short f2bf(float f) {
  union { float f; unsigned i; } x; x.f = f;
  unsigned r = x.i + 0x7FFFu + ((x.i >> 16) & 1u);
  return (unsigned short)(r >> 16);
}

// ---------------- XCD-chunked bijective block swizzle (m204) ----------------
__device__ __forceinline__ unsigned swz8(unsigned orig, unsigned nwg) {
  unsigned q = nwg >> 3, r = nwg & 7;
  unsigned xcd = orig & 7, off = orig >> 3;
  unsigned base = (xcd < r) ? xcd * (q + 1) : r * (q + 1) + (xcd - r) * q;
  return base + off;
}

// ---------------- graph preprocessing ----------------
__global__ void __launch_bounds__(256) k_edge_count(const int* __restrict__ ei, int E,
                                                    float* __restrict__ degf, int* __restrict__ indeg) {
  int e = blockIdx.x * 256 + threadIdx.x;
  if (e >= E) return;
  int s = ei[e], d = ei[E + e];
  if (s != d) {
    atomicAdd(&degf[s], 1.0f);
    atomicAdd(&indeg[d], 1);
  }
}

__global__ void __launch_bounds__(256) k_dinv(const float* __restrict__ degf, float* __restrict__ dinv) {
  int n = blockIdx.x * 256 + threadIdx.x;
  if (n >= NN) return;
  float d = degf[n];
  dinv[n] = d > 0.f ? rsqrtf(d) : 0.f;
}

__global__ void __launch_bounds__(1024) k_scan(const int* __restrict__ indeg, int* __restrict__ rowptr) {
  __shared__ int part[1024];
  const int chunk = (NN + 1023) / 1024;
  int t = threadIdx.x;
  int beg = t * chunk, end = min(beg + chunk, NN);
  int s = 0;
  for (int i = beg; i < end; ++i) s += indeg[i];
  part[t] = s;
  __syncthreads();
  if (t == 0) {
    int run = 0;
    for (int i = 0; i < 1024; ++i) { int v = part[i]; part[i] = run; run += v; }
    rowptr[NN] = run;
  }
  __syncthreads();
  int run = part[t];
  for (int i = beg; i < end; ++i) { rowptr[i] = run; run += indeg[i]; }
}

__global__ void __launch_bounds__(256) k_fill(const int* __restrict__ ei, int E,
                                              const float* __restrict__ dinv,
                                              const int* __restrict__ rowptr,
                                              int* __restrict__ cursor,
                                              int* __restrict__ col, float* __restrict__ wcs) {
  int e = blockIdx.x * 256 + threadIdx.x;
  if (e >= E) return;
  int s = ei[e], d = ei[E + e];
  if (s != d) {
    int p = atomicAdd(&cursor[d], 1);
    int o = rowptr[d] + p;
    col[o] = s;
    wcs[o] = -dinv[s] * dinv[d];
  }
}

// ---------------- cheb weight pack into MFMA B-fragment order (bf16) ----------------
__global__ void __launch_bounds__(256) k_wpack(const float* __restrict__ W, unsigned short* __restrict__ Wp) {
  int id = blockIdx.x * 256 + threadIdx.x;  // 6*256 = 24 frags * 64 lanes
  int f = id >> 6, l = id & 63;
  int kk = f >> 2, jt = f & 3;
  int kcheb = kk >> 1;
  int cout = jt * 16 + (l & 15);
#pragma unroll
  for (int e = 0; e < 8; ++e) {
    int cin = (kk & 1) * 32 + (l >> 4) * 8 + e;
    Wp[(size_t)f * 512 + l * 8 + e] = f2bf(W[(size_t)kcheb * 4096 + cin * 64 + cout]);
  }
}

// ---------------- temporal conv 1: (B,T,N,2) -> per-b bf16 (10,N,64) ----------------
__global__ void __launch_bounds__(256) k_tc1(const float* __restrict__ x, const float* __restrict__ W,
                                             const float* __restrict__ Bv, unsigned short* __restrict__ out, int b) {
  __shared__ float ws[1152];
  __shared__ float bs[192];
  for (int i = threadIdx.x; i < 1152; i += 256) ws[i] = W[i];
  for (int i = threadIdx.x; i < 192; i += 256) bs[i] = Bv[i];
  __syncthreads();
  long tid = (long)blockIdx.x * 256 + threadIdx.x;
  if (tid >= ROWS * 64) return;
  int co = (int)(tid & 63);
  int n  = (int)((tid >> 6) % NN);
  int to = (int)(tid / (64L * NN));
  float aP = bs[co], aQ = bs[64 + co], aR = bs[128 + co];
#pragma unroll
  for (int k = 0; k < 3; ++k) {
#pragma unroll
    for (int ci = 0; ci < 2; ++ci) {
      float xv = x[(((long)b * TT + to + k) * NN + n) * FIN + ci];
      int wi = (k * 2 + ci) * 64 + co;
      aP = fmaf(xv, ws[wi], aP);
      aQ = fmaf(xv, ws[384 + wi], aQ);
      aR = fmaf(xv, ws[768 + wi], aR);
    }
  }
  float sq = 1.f / (1.f + expf(-aQ));
  out[tid] = f2bf(fmaxf(aP * sq + aR, 0.f));
}

// ---------------- bf16 CSR propagation, edge-parallel (8 edges in flight) ----------------
// wave = 1 (slice,node); lane = eq*8+cl; each edge-group loads 128B (8 lanes x ushort8)
__global__ void __launch_bounds__(256) k_prop_bf(const unsigned short* __restrict__ v,
                                                 unsigned short* __restrict__ out,
                                                 const unsigned short* __restrict__ xin,
                                                 const int* __restrict__ rowptr, const int* __restrict__ col,
                                                 const float* __restrict__ wcs) {
  unsigned bid = swz8(blockIdx.x, gridDim.x);
  long tid = (long)bid * 256 + threadIdx.x;
  long ng = tid >> 6;
  if (ng >= ROWS) return;
  int lane = threadIdx.x & 63;
  int eq = lane >> 3, cl = lane & 7;
  int s = (int)(ng / NN);
  int n = (int)(ng % NN);
  n = __builtin_amdgcn_readfirstlane(n);
  s = __builtin_amdgcn_readfirstlane(s);
  int beg = rowptr[n], end = rowptr[n + 1];
  const unsigned short* vs = v + (long)s * NN * 64;
  float acc[8] = {0.f, 0.f, 0.f, 0.f, 0.f, 0.f, 0.f, 0.f};
  for (int e0 = beg; e0 < end; e0 += 8) {
    int e = e0 + eq;
    bool val = e < end;
    float w = val ? wcs[e] : 0.f;
    int cc = val ? col[e] : col[beg];
    short8v a = *(const short8v*)(vs + (long)cc * 64 + cl * 8);
#pragma unroll
    for (int k = 0; k < 8; ++k)
      acc[k] = fmaf(w, bf2f((unsigned short)a[k]), acc[k]);
  }
#pragma unroll
  for (int k = 0; k < 8; ++k) {
    acc[k] += __shfl_xor(acc[k], 8);
    acc[k] += __shfl_xor(acc[k], 16);
    acc[k] += __shfl_xor(acc[k], 32);
  }
  if (eq == 0) {
    long ob = ng * 64 + cl * 8;
    short8v o;
    if (xin) {
      short8v xi = *(const short8v*)(xin + ob);
#pragma unroll
      for (int k = 0; k < 8; ++k) o[k] = (short)f2bf(2.f * acc[k] - bf2f((unsigned short)xi[k]));
    } else {
#pragma unroll
      for (int k = 0; k < 8; ++k) o[k] = (short)f2bf(acc[k]);
    }
    *(short8v*)(out + ob) = o;
  }
}

// ---------------- Cheb combine via MFMA ----------------
__global__ void __launch_bounds__(256) k_cheb_mfma(const unsigned short* __restrict__ Xb,
                                                   const unsigned short* __restrict__ T1b,
                                                   const unsigned short* __restrict__ T2b,
                                                   const unsigned short* __restrict__ Wp,
                                                   const float* __restrict__ Bv,
                                                   float* __restrict__ H2) {
  int wid = threadIdx.x >> 6, lane = threadIdx.x & 63;
  long tile = (long)blockIdx.x * 4 + wid;
  if (tile >= ROWS / 16) return;
  int r = lane & 15, g = lane >> 4;
  short8v wf[24];
#pragma unroll
  for (int f = 0; f < 24; ++f)
    wf[f] = *(const short8v*)(Wp + (size_t)f * 512 + lane * 8);
  float bias[4];
#pragma unroll
  for (int jt = 0; jt < 4; ++jt) bias[jt] = Bv[jt * 16 + r];
  long rowbase = tile * 16;
  f32x4 acc[4];
#pragma unroll
  for (int jt = 0; jt < 4; ++jt) acc[jt] = (f32x4){0.f, 0.f, 0.f, 0.f};
  const unsigned short* srcs[3] = {Xb, T1b, T2b};
#pragma unroll
  for (int kk = 0; kk < 6; ++kk) {
    const unsigned short* S = srcs[kk >> 1];
    short8v a = *(const short8v*)(S + (rowbase + r) * 64 + (kk & 1) * 32 + g * 8);
#pragma unroll
    for (int jt = 0; jt < 4; ++jt)
      acc[jt] = __builtin_amdgcn_mfma_f32_16x16x32_bf16(a, wf[kk * 4 + jt], acc[jt], 0, 0, 0);
  }
#pragma unroll
  for (int jt = 0; jt < 4; ++jt)
#pragma unroll
    for (int reg = 0; reg < 4; ++reg) {
      int m = 4 * g + reg;
      H2[(rowbase + m) * 64 + jt * 16 + r] = fmaxf(acc[jt][reg] + bias[jt], 0.f);
    }
}

// ---------------- temporal conv 2: per-b (10,N,64) -> h3[t*4+b][n][8] (padded) ----------------
__global__ void __launch_bounds__(256) k_tc2(const float4* __restrict__ h2, const float* __restrict__ W,
                                             const float* __restrict__ Bv, float* __restrict__ h3, int b) {
  long tid = (long)blockIdx.x * 256 + threadIdx.x;
  if (tid >= (long)T2n * NN) return;
  int t2 = (int)(tid / NN), n = (int)(tid % NN);
  float p[5], q[5], r[5];
#pragma unroll
  for (int co = 0; co < 5; ++co) { p[co] = Bv[co]; q[co] = Bv[5 + co]; r[co] = Bv[10 + co]; }
#pragma unroll
  for (int k = 0; k < 3; ++k) {
    const float4* rowp = h2 + ((long)(t2 + k) * NN + n) * 16;
    for (int c4 = 0; c4 < 16; ++c4) {
      float4 vv = rowp[c4];
      const float* w = W + ((k * 64) + c4 * 4) * 5;
#pragma unroll
      for (int co = 0; co < 5; ++co) {
        p[co] += vv.x * w[co]        + vv.y * w[5 + co]    + vv.z * w[10 + co]   + vv.w * w[15 + co];
        q[co] += vv.x * w[960 + co]  + vv.y * w[965 + co]  + vv.z * w[970 + co]  + vv.w * w[975 + co];
        r[co] += vv.x * w[1920 + co] + vv.y * w[1925 + co] + vv.z * w[1930 + co] + vv.w * w[1935 + co];
      }
    }
  }
  float o[5];
#pragma unroll
  for (int co = 0; co < 5; ++co) {
    float sq = 1.f / (1.f + expf(-q[co]));
    o[co] = fmaxf(p[co] * sq + r[co], 0.f);
  }
  float4* dst = (float4*)(h3 + ((long)(t2 * 4 + b) * NN + n) * 8);
  dst[0] = make_float4(o[0], o[1], o[2], o[3]);
  dst[1] = make_float4(o[4], 0.f, 0.f, 0.f);
}

// ---------------- BatchNorm (padded rows of 8) ----------------
__global__ void __launch_bounds__(256) k_bn_stats(const float* __restrict__ h3,
                                                  const float* __restrict__ gamma,
                                                  const float* __restrict__ beta,
                                                  float* __restrict__ bnS, float* __restrict__ bnH) {
  long tid = (long)blockIdx.x * 256 + threadIdx.x;
  if (tid >= 4L * NN) return;
  int q = (int)(tid & 3);
  int n = (int)(tid >> 2);
  float s1 = 0.f, s2 = 0.f;
  for (int t = q * 2; t < q * 2 + 2; ++t)
    for (int b = 0; b < 4; ++b) {
      const float* p = h3 + ((long)(t * 4 + b) * NN + n) * 8;
#pragma unroll
      for (int co = 0; co < 5; ++co) { float v = p[co]; s1 += v; s2 += v * v; }
    }
  s1 += __shfl_xor(s1, 1, 4); s1 += __shfl_xor(s1, 2, 4);
  s2 += __shfl_xor(s2, 1, 4); s2 += __shfl_xor(s2, 2, 4);
  if (q == 0) {
    float mean = s1 * (1.f / 160.f);
    float var = s2 * (1.f / 160.f) - mean * mean;
    float sc = gamma[n] * rsqrtf(var + 1e-5f);
    bnS[n] = sc;
    bnH[n] = beta[n] - mean * sc;
  }
}

__global__ void __launch_bounds__(256) k_bn_apply(float* __restrict__ h3,
                                                  const float* __restrict__ bnS,
                                                  const float* __restrict__ bnH) {
  long tid = (long)blockIdx.x * 256 + threadIdx.x;
  if (tid >= 32L * NN * 8) return;
  int n = (int)((tid >> 3) % NN);
  h3[tid] = fmaxf(h3[tid] * bnS[n] + bnH[n], 0.f);
}

// ---------------- PX precompute: edge-parallel, lane = whole edge (padded rows) ----------------
__global__ void __launch_bounds__(256) k_prop5(const float* __restrict__ h3, float* __restrict__ PX,
                                               const int* __restrict__ rowptr, const int* __restrict__ col,
                                               const float* __restrict__ wcs) {
  unsigned bid = swz8(blockIdx.x, gridDim.x);
  long tid = (long)bid * 256 + threadIdx.x;
  long ng = tid >> 3;
  int eq = (int)(tid & 7);
  if (ng >= 32L * NN) return;
  int s = (int)(ng / NN), n = (int)(ng % NN);
  int beg = rowptr[n], end = rowptr[n + 1];
  const float* src = h3 + (long)s * NN * 8;
  float a0 = 0.f, a1 = 0.f, a2 = 0.f, a3 = 0.f, a4 = 0.f;
  for (int e0 = beg; e0 < end; e0 += 8) {
    int e = e0 + eq;
    bool val = e < end;
    float w = val ? wcs[e] : 0.f;
    int cc = val ? col[e] : col[beg];
    const float* row = src + (long)cc * 8;
    float4 v = *(const float4*)row;
    float v4 = row[4];
    a0 = fmaf(w, v.x, a0); a1 = fmaf(w, v.y, a1); a2 = fmaf(w, v.z, a2);
    a3 = fmaf(w, v.w, a3); a4 = fmaf(w, v4, a4);
  }
#pragma unroll
  for (int m = 1; m <= 4; m <<= 1) {
    a0 += __shfl_xor(a0, m); a1 += __shfl_xor(a1, m); a2 += __shfl_xor(a2, m);
    a3 += __shfl_xor(a3, m); a4 += __shfl_xor(a4, m);
  }
  if (eq == 0) {
    float* dst = PX + ng * 8;
    *(float4*)dst = make_float4(a0, a1, a2, a3);
    dst[4] = a4;
  }
}

// ---------------- fused GRU step kernels (edge-parallel gathers) ----------------
__global__ void __launch_bounds__(256) k_gru1(const float* __restrict__ h3, const float* __restrict__ PX,
                                              const float* __restrict__ Hp,
                                              const int* __restrict__ rowptr, const int* __restrict__ col,
                                              const float* __restrict__ wcs,
                                              const float* __restrict__ gwx, const float* __restrict__ gbx,
                                              const float* __restrict__ gwh, const float* __restrict__ gbh,
                                              float* __restrict__ Z, float* __restrict__ HR, int t) {
  __shared__ float swh[4096];
  __shared__ float swx[640];
  for (int i = threadIdx.x; i < 4096; i += 256) swh[i] = gwh[i];
  for (int i = threadIdx.x; i < 640; i += 256) swx[i] = gwx[i];
  __syncthreads();
  unsigned bid = swz8(blockIdx.x, gridDim.x);
  long tid = (long)bid * 256 + threadIdx.x;
  long ng = tid >> 5;
  int j = (int)(tid & 31);
  if (ng >= 4L * NN) return;
  int b = (int)(ng / NN), n = (int)(ng % NN);
  long hrow = ng * 32;
  long xrow = ((long)(t * 4 + b) * NN + n) * 8;
  const float* hsrc = Hp + (long)b * NN * 32;
  float hv = Hp[hrow + j];
  // 4-way edge-parallel gather of ph
  int eq = j >> 3, cl = j & 7;
  int beg = rowptr[n], end = rowptr[n + 1];
  float4 pa = make_float4(0.f, 0.f, 0.f, 0.f);
  for (int e0 = beg; e0 < end; e0 += 4) {
    int e = e0 + eq;
    bool val = e < end;
    float w = val ? wcs[e] : 0.f;
    int cc = val ? col[e] : col[beg];
    float4 hh = *(const float4*)(hsrc + (long)cc * 32 + cl * 4);
    pa.x = fmaf(w, hh.x, pa.x); pa.y = fmaf(w, hh.y, pa.y);
    pa.z = fmaf(w, hh.z, pa.z); pa.w = fmaf(w, hh.w, pa.w);
  }
  pa.x += __shfl_xor(pa.x, 8);  pa.y += __shfl_xor(pa.y, 8);
  pa.z += __shfl_xor(pa.z, 8);  pa.w += __shfl_xor(pa.w, 8);
  pa.x += __shfl_xor(pa.x, 16); pa.y += __shfl_xor(pa.y, 16);
  pa.z += __shfl_xor(pa.z, 16); pa.w += __shfl_xor(pa.w, 16);
  float v0 = __shfl(pa.x, j >> 2, 32);
  float v1 = __shfl(pa.y, j >> 2, 32);
  float v2 = __shfl(pa.z, j >> 2, 32);
  float v3 = __shfl(pa.w, j >> 2, 32);
  int pp = j & 3;
  float ph = pp == 0 ? v0 : pp == 1 ? v1 : pp == 2 ? v2 : v3;

  float az = gbx[j] + gbh[j];
  float ar = gbx[32 + j] + gbh[32 + j];
#pragma unroll
  for (int ci = 0; ci < 5; ++ci) {
    float xv = h3[xrow + ci], pv = PX[xrow + ci];
    az += xv * swx[ci * 32 + j] + pv * swx[160 + ci * 32 + j];
    ar += xv * swx[320 + ci * 32 + j] + pv * swx[480 + ci * 32 + j];
  }
#pragma unroll
  for (int ci = 0; ci < 32; ++ci) {
    float hb = __shfl(hv, ci, 32);
    float pb = __shfl(ph, ci, 32);
    az += hb * swh[ci * 32 + j] + pb * swh[1024 + ci * 32 + j];
    ar += hb * swh[2048 + ci * 32 + j] + pb * swh[3072 + ci * 32 + j];
  }
  float zz = 1.f / (1.f + expf(-az));
  float rr = 1.f / (1.f + expf(-ar));
  Z[hrow + j] = zz;
  HR[hrow + j] = hv * rr;
}

__global__ void __launch_bounds__(256) k_gru2(const float* __restrict__ h3, const float* __restrict__ PX,
                                              const float* __restrict__ Hp, const float* __restrict__ Z,
                                              const float* __restrict__ HR,
                                              const int* __restrict__ rowptr, const int* __restrict__ col,
                                              const float* __restrict__ wcs,
                                              const float* __restrict__ gwx, const float* __restrict__ gbx,
                                              const float* __restrict__ gwh, const float* __restrict__ gbh,
                                              const float* __restrict__ lw, const float* __restrict__ lb,
                                              float* __restrict__ Hn, float* __restrict__ logits, int t) {
  __shared__ float swh[2048];
  __shared__ float swx[320];
  for (int i = threadIdx.x; i < 2048; i += 256) swh[i] = gwh[4096 + i];
  for (int i = threadIdx.x; i < 320; i += 256) swx[i] = gwx[640 + i];
  __syncthreads();
  unsigned bid = swz8(blockIdx.x, gridDim.x);
  long tid = (long)bid * 256 + threadIdx.x;
  long ng = tid >> 5;
  int j = (int)(tid & 31);
  if (ng >= 4L * NN) return;
  int b = (int)(ng / NN), n = (int)(ng % NN);
  long hrow = ng * 32;
  long xrow = ((long)(t * 4 + b) * NN + n) * 8;
  const float* hsrc = HR + (long)b * NN * 32;
  float hrv = HR[hrow + j];
  int eq = j >> 3, cl = j & 7;
  int beg = rowptr[n], end = rowptr[n + 1];
  float4 pa = make_float4(0.f, 0.f, 0.f, 0.f);
  for (int e0 = beg; e0 < end; e0 += 4) {
    int e = e0 + eq;
    bool val = e < end;
    float w = val ? wcs[e] : 0.f;
    int cc = val ? col[e] : col[beg];
    float4 hh = *(const float4*)(hsrc + (long)cc * 32 + cl * 4);
    pa.x = fmaf(w, hh.x, pa.x); pa.y = fmaf(w, hh.y, pa.y);
    pa.z = fmaf(w, hh.z, pa.z); pa.w = fmaf(w, hh.w, pa.w);
  }
  pa.x += __shfl_xor(pa.x, 8);  pa.y += __shfl_xor(pa.y, 8);
  pa.z += __shfl_xor(pa.z, 8);  pa.w += __shfl_xor(pa.w, 8);
  pa.x += __shfl_xor(pa.x, 16); pa.y += __shfl_xor(pa.y, 16);
  pa.z += __shfl_xor(pa.z, 16); pa.w += __shfl_xor(pa.w, 16);
  float v0 = __shfl(pa.x, j >> 2, 32);
  float v1 = __shfl(pa.y, j >> 2, 32);
  float v2 = __shfl(pa.z, j >> 2, 32);
  float v3 = __shfl(pa.w, j >> 2, 32);
  int pp = j & 3;
  float phr = pp == 0 ? v0 : pp == 1 ? v1 : pp == 2 ? v2 : v3;

  float a = gbx[64 + j] + gbh[64 + j];
#pragma unroll
  for (int ci = 0; ci < 5; ++ci) {
    float xv = h3[xrow + ci], pv = PX[xrow + ci];
    a += xv * swx[ci * 32 + j] + pv * swx[160 + ci * 32 + j];
  }
#pragma unroll
  for (int ci = 0; ci < 32; ++ci) {
    float hb = __shfl(hrv, ci, 32);
    float pb = __shfl(phr, ci, 32);
    a += hb * swh[ci * 32 + j] + pb * swh[1024 + ci * 32 + j];
  }
  float zz = Z[hrow + j];
  float hn = zz * Hp[hrow + j] + (1.f - zz) * tanhf(a);
  Hn[hrow + j] = hn;
  float c = fmaxf(hn, 0.f) * lw[j];
  c += __shfl_xor(c, 16, 32);
  c += __shfl_xor(c, 8, 32);
  c += __shfl_xor(c, 4, 32);
  c += __shfl_xor(c, 2, 32);
  c += __shfl_xor(c, 1, 32);
  if (j == 0) logits[((long)b * 8 + t) * NN + n] = c + lb[0];
}

// ---------------- final log_softmax over the 8 time steps ----------------
__global__ void __launch_bounds__(256) k_logsoftmax(const float* __restrict__ logits, float* __restrict__ out) {
  long tid = (long)blockIdx.x * 256 + threadIdx.x;
  if (tid >= 4L * NN) return;
  int b = (int)(tid / NN), n = (int)(tid % NN);
  float l[8];
#pragma unroll
  for (int t = 0; t < 8; ++t) l[t] = logits[((long)b * 8 + t) * NN + n];
  float m = l[0];
#pragma unroll
  for (int t = 1; t < 8; ++t) m = fmaxf(m, l[t]);
  float s = 0.f;
#pragma unroll
  for (int t = 0; t < 8; ++t) s += expf(l[t] - m);
  float lse = m + logf(s);
#pragma unroll
  for (int t = 0; t < 8; ++t) out[((long)b * 8 + t) * NN + n] = l[t] - lse;
}

// ---------------- host orchestration ----------------
extern "C" void kernel_launch(void* const* d_in, const int* in_sizes, int n_in,
                              void* d_out, int out_size, void* d_ws, size_t ws_size,
                              hipStream_t stream) {
  const float* x     = (const float*)d_in[0];
  const int*   ei    = (const int*)d_in[1];
  const float* tc1w  = (const float*)d_in[2];
  const float* tc1b  = (const float*)d_in[3];
  const float* chebw = (const float*)d_in[4];
  const float* chebb = (const float*)d_in[5];
  const float* tc2w  = (const float*)d_in[6];
  const float* tc2b  = (const float*)d_in[7];
  const float* gam   = (const float*)d_in[8];
  const float* bet   = (const float*)d_in[9];
  const float* gwx   = (const float*)d_in[10];
  const float* gbx   = (const float*)d_in[11];
  const float* gwh   = (const float*)d_in[12];
  const float* gbh   = (const float*)d_in[13];
  const float* lw    = (const float*)d_in[14];
  const float* lb    = (const float*)d_in[15];
  float* out = (float*)d_out;
  int E = in_sizes[1] / 2;
  if (ws_size < WS_NEED) return;

  char* ws = (char*)d_ws;
  unsigned short* Xb  = (unsigned short*)(ws + O_XB);
  unsigned short* T1b = (unsigned short*)(ws + O_T1B);
  unsigned short* T2b = (unsigned short*)(ws + O_T2B);
  float* H2   = (float*)(ws + O_H2);
  float* h3   = (float*)(ws + O_H3);
  float* PX   = (float*)(ws + O_PX);
  float* bnS  = (float*)(ws + O_BNS);
  float* bnH  = (float*)(ws + O_BNH);
  float* degf = (float*)(ws + O_DEG);
  int*   ind  = (int*)(ws + O_IND);
  int*   cur  = (int*)(ws + O_CUR);
  float* dnv  = (float*)(ws + O_DNV);
  int*   rp   = (int*)(ws + O_RP);
  int*   col  = (int*)(ws + O_COL);
  float* wcs  = (float*)(ws + O_WCS);
  float* lg   = (float*)(ws + O_LG);
  unsigned short* Wp = (unsigned short*)(ws + O_WP);
  float* Hp  = (float*)(ws + O_XB);
  float* Hn  = (float*)(ws + O_XB + SZ_H);
  float* Zb  = (float*)(ws + O_XB + 2 * SZ_H);
  float* HRb = (float*)(ws + O_XB + 3 * SZ_H);

  // --- graph prep + weight pack ---
  hipMemsetAsync(ws + O_DEG, 0, 240000, stream);
  unsigned gE = (unsigned)((E + 255) / 256);
  k_edge_count<<<gE, 256, 0, stream>>>(ei, E, degf, ind);
  k_dinv<<<(NN + 255) / 256, 256, 0, stream>>>(degf, dnv);
  k_scan<<<1, 1024, 0, stream>>>(ind, rp);
  k_fill<<<gE, 256, 0, stream>>>(ei, E, dnv, rp, cur, col, wcs);
  k_wpack<<<6, 256, 0, stream>>>(chebw, Wp);

  // --- per-batch STConv pipeline ---
  unsigned g64 = (unsigned)((ROWS * 64 + 255) / 256);  // 50000
  for (int b = 0; b < 4; ++b) {
    k_tc1<<<g64, 256, 0, stream>>>(x, tc1w, tc1b, Xb, b);
    k_prop_bf<<<g64, 256, 0, stream>>>(Xb, T1b, nullptr, rp, col, wcs);
    k_prop_bf<<<g64, 256, 0, stream>>>(T1b, T2b, Xb, rp, col, wcs);
    k_cheb_mfma<<<(unsigned)(ROWS / 16 / 4), 256, 0, stream>>>(Xb, T1b, T2b, Wp, chebb, H2);
    k_tc2<<<(unsigned)(((long)T2n * NN + 255) / 256), 256, 0, stream>>>(
        (const float4*)H2, tc2w, tc2b, h3, b);
  }

  // --- BatchNorm (per node) + relu ---
  k_bn_stats<<<(4 * NN + 255) / 256, 256, 0, stream>>>(h3, gam, bet, bnS, bnH);
  k_bn_apply<<<(unsigned)((32L * NN * 8 + 255) / 256), 256, 0, stream>>>(h3, bnS, bnH);

  // --- precompute prop(Xt) for all 32 (t,b) slices ---
  k_prop5<<<(unsigned)((32L * NN * 8 + 255) / 256), 256, 0, stream>>>(h3, PX, rp, col, wcs);

  // --- GConvGRU, 8 sequential steps ---
  hipMemsetAsync(Hp, 0, SZ_H, stream);
  float* hp = Hp;
  float* hn = Hn;
  unsigned gG = (unsigned)((4L * NN * 32 + 255) / 256);  // 10000
  for (int t = 0; t < 8; ++t) {
    k_gru1<<<gG, 256, 0, stream>>>(h3, PX, hp, rp, col, wcs, gwx, gbx, gwh, gbh, Zb, HRb, t);
    k_gru2<<<gG, 256, 0, stream>>>(h3, PX, hp, Zb, HRb, rp, col, wcs, gwx, gbx, gwh, gbh,
                                   lw, lb, hn, lg, t);
    float* tmp = hp; hp = hn; hn = tmp;
  }

  unsigned gN = (unsigned)((4L * NN + 255) / 256);
  k_logsoftmax<<<gN, 256, 0, stream>>>(lg, out);
}